// Round 5
// baseline (489.619 us; speedup 1.0000x reference)
//
#include <hip/hip_runtime.h>
#include <stdint.h>

#define N_  8
#define CK  128
#define CV  512
#define HW  900     // 30*30 queries
#define M_  7200    // 8*30*30 memory slots
#define QK_SCALE 0.08838834764831845f  // 1/sqrt(128)

typedef __attribute__((ext_vector_type(8))) short  short8;
typedef __attribute__((ext_vector_type(4))) float  floatx4;
typedef __attribute__((ext_vector_type(4))) unsigned int   uintx4;
typedef __attribute__((ext_vector_type(4))) unsigned short ushortx4;

__device__ __forceinline__ uint16_t f32_to_bf16(float x) {
    union { float f; uint32_t u; } v; v.f = x;
    return (uint16_t)((v.u + 0x7FFFu + ((v.u >> 16) & 1u)) >> 16);
}

// Direct HBM -> LDS DMA, 16 B per lane. LDS dest is wave-uniform base
// (hardware adds lane*16B); global src is per-lane.
__device__ __forceinline__ void gload_lds16(const uint16_t* g, short* l) {
    __builtin_amdgcn_global_load_lds(
        (const __attribute__((address_space(1))) void*)g,
        (__attribute__((address_space(3))) void*)l,
        16, 0, 0);
}

// counted-vmcnt wait: loads stay in flight across barriers (T4)
#define WAITV(n) asm volatile("s_waitcnt vmcnt(" #n ")" ::: "memory")
// full fence barrier: sched_barrier on BOTH sides so no memory op (incl.
// global_load_lds) migrates across the s_barrier (m152 race class).
#define BARRIER() do { __builtin_amdgcn_sched_barrier(0); \
                       __builtin_amdgcn_s_barrier(); \
                       __builtin_amdgcn_sched_barrier(0); } while (0)

// ---------------------------------------------------------------- zero dsum
__global__ void k_zero(float* __restrict__ p) {
    int i = blockIdx.x * 256 + threadIdx.x;
    if (i < N_ * M_) p[i] = 0.f;
}

// ---------------------------------------------------------------- q_val copy (channels 0..511)
__global__ __launch_bounds__(256) void k_copy_qval(const float* __restrict__ qv,
                                                   float* __restrict__ out) {
    unsigned i = blockIdx.x * 256 + threadIdx.x;
    unsigned e = i * 4u;
    unsigned n = e / (CV * HW);
    unsigned off = e - n * (CV * HW);
    *(floatx4*)&out[(size_t)n * (2 * CV * HW) + off] = *(const floatx4*)&qv[e];
}

// ---------------------------------------------------------------- transpose [N][CK][L] fp32 -> [N][L][CK] bf16
__global__ __launch_bounds__(256) void k_trans(const float* __restrict__ in,
                                               uint16_t* __restrict__ outp, int L) {
    __shared__ float tile[32][33];
    const int tx = threadIdx.x & 31;
    const int ty = threadIdx.x >> 5;      // 0..7
    const int l0 = blockIdx.x * 32;
    const int c0 = blockIdx.y * 32;
    const int n  = blockIdx.z;
    const float* src = in + (size_t)n * CK * L;
    uint16_t* dst = outp + (size_t)n * L * CK;
#pragma unroll
    for (int p = 0; p < 4; p++) {
        int c = c0 + p * 8 + ty;
        int l = l0 + tx;
        float v = 0.f;
        if (l < L) v = src[(size_t)c * L + l];
        tile[p * 8 + ty][tx] = v;
    }
    __syncthreads();
#pragma unroll
    for (int p = 0; p < 4; p++) {
        int l = l0 + p * 8 + ty;
        int c = c0 + tx;
        if (l < L) dst[(size_t)l * CK + c] = f32_to_bf16(tile[tx][p * 8 + ty]);
    }
}

// ---------------------------------------------------------------- K1: aff = qkT mkT^T, exp, colsum
// Counted-vmcnt 4-buffer pipeline (BK=32, prefetch depth 3) — round-4 verbatim.
#define K1_TS 144   // C-tile stride (shorts)

__global__ __launch_bounds__(256) void k1_gemm_exp(
    const uint16_t* __restrict__ qkT,  // [N][HW][CK] bf16 (A: rows q, k=c)
    const uint16_t* __restrict__ mkT,  // [N][M][CK] bf16  (B: rows m, k=c)
    uint16_t* __restrict__ E,          // [N][HW][M] bf16 = exp(aff*scale)
    float* __restrict__ dsum)          // [N][M]
{
    __shared__ __align__(16) short smem[32768];   // 4 bufs x (A 4096 + B 4096)
    __shared__ float colsum[128];

    // XCD swizzle: 3648 blocks, 456/XCD = exactly one n-plane per XCD.
    const int bid = blockIdx.x + 57 * (blockIdx.y + 8 * blockIdx.z);
    const int swz = (bid & 7) * 456 + (bid >> 3);
    const int mb   = swz % 57;
    const int rest = swz / 57;
    const int m0 = mb * 128;
    const int q0 = (rest & 7) * 128;
    const int n  = rest >> 3;
    const int tid = threadIdx.x;

    if (tid < 128) colsum[tid] = 0.f;

    const int lane = tid & 63;
    const int wid  = tid >> 6;
    const int wq   = (wid >> 1) << 6;
    const int wm   = (wid & 1) << 6;
    const int fr   = lane & 15;
    const int quad = lane >> 4;

    const int ca = wid * 2;
    const int rr = lane >> 2;        // row within chunk 0..15
    const int cc = (lane & 3) * 8;   // col (shorts), 16B aligned

    const uint16_t* Ab = qkT + (size_t)n * HW * CK;
    const uint16_t* Bb = mkT + (size_t)n * M_ * CK;
    const uint16_t* A0p = Ab + (size_t)(q0 + ca * 16 + rr) * CK + cc;
    const uint16_t* A1p = A0p + 16 * CK;
    const uint16_t* B0p = Bb + (size_t)(m0 + ca * 16 + rr) * CK + cc;
    const uint16_t* B1p = B0p + 16 * CK;

    floatx4 acc[4][4];
#pragma unroll
    for (int a = 0; a < 4; a++)
#pragma unroll
        for (int b = 0; b < 4; b++) acc[a][b] = (floatx4){0.f, 0.f, 0.f, 0.f};

#define K1_STAGE(buf, ko) do { \
    short* dA = smem + (buf) * 8192 + ca * 512; \
    short* dB = dA + 4096; \
    gload_lds16(A0p + (ko), dA); \
    gload_lds16(A1p + (ko), dA + 512); \
    gload_lds16(B0p + (ko), dB); \
    gload_lds16(B1p + (ko), dB + 512); \
} while (0)

#define K1_COMPUTE(buf) do { \
    const short* bA = smem + (buf) * 8192; \
    const short* bB = bA + 4096; \
    const int k0 = quad * 8; \
    short8 af[4], bfr[4]; \
    _Pragma("unroll") \
    for (int t = 0; t < 4; t++) \
        af[t] = *(const short8*)&bA[(wq + t * 16 + fr) * 32 + k0]; \
    _Pragma("unroll") \
    for (int t = 0; t < 4; t++) \
        bfr[t] = *(const short8*)&bB[(wm + t * 16 + fr) * 32 + k0]; \
    _Pragma("unroll") \
    for (int tq = 0; tq < 4; tq++) \
        _Pragma("unroll") \
        for (int tm = 0; tm < 4; tm++) \
            acc[tq][tm] = __builtin_amdgcn_mfma_f32_16x16x32_bf16( \
                af[tq], bfr[tm], acc[tq][tm], 0, 0, 0); \
} while (0)

    // prefetch depth 3 over 4 K-steps (CK=128, BK=32)
    K1_STAGE(0, 0); K1_STAGE(1, 32); K1_STAGE(2, 64);
    WAITV(8); BARRIER(); K1_STAGE(3, 96); K1_COMPUTE(0);   // t=0
    WAITV(8); BARRIER(); K1_COMPUTE(1);                    // t=1
    WAITV(4); BARRIER(); K1_COMPUTE(2);                    // t=2
    WAITV(0); BARRIER(); K1_COMPUTE(3);                    // t=3

    // ---- epilogue phase A: exp -> LDS C-tile (stride 144), colsum
    __syncthreads();   // all frag reads done; smem reusable as C-tile
    float cs[4] = {0.f, 0.f, 0.f, 0.f};
#pragma unroll
    for (int tq = 0; tq < 4; tq++) {
#pragma unroll
        for (int tm = 0; tm < 4; tm++) {
            const int col = wm + tm * 16 + fr;
#pragma unroll
            for (int i = 0; i < 4; i++) {
                const int row = wq + tq * 16 + quad * 4 + i;
                float e = __expf(acc[tq][tm][i] * QK_SCALE);
                if (q0 + row < HW) cs[tm] += e;   // guard: padded q-rows must not pollute colsum
                smem[row * K1_TS + col] = (short)f32_to_bf16(e);
            }
        }
    }
#pragma unroll
    for (int tm = 0; tm < 4; tm++) {
        float s = cs[tm];
        s += __shfl_xor(s, 16, 64);
        s += __shfl_xor(s, 32, 64);
        if (quad == 0) atomicAdd(&colsum[wm + tm * 16 + fr], s);
    }
    __syncthreads();   // C-tile complete + colsum complete

    // ---- epilogue phase B: coalesced uint4 E-writes (8 per thread)
    uint16_t* En = E + (size_t)n * HW * M_;
#pragma unroll
    for (int j = 0; j < 8; j++) {
        int idx = tid + j * 256;       // 0..2047 = 128 rows x 16 uint4
        int r   = idx >> 4;
        int c8  = (idx & 15) * 8;      // short offset in row
        if (q0 + r < HW && m0 + c8 + 8 <= M_) {
            uintx4 v = *(const uintx4*)&smem[r * K1_TS + c8];
            *(uintx4*)&En[(size_t)(q0 + r) * M_ + m0 + c8] = v;
        }
    }
    if (tid < 128) {
        const int gm = m0 + tid;
        if (gm < M_) atomicAdd(&dsum[(size_t)n * M_ + gm], colsum[tid]);
    }
#undef K1_STAGE
#undef K1_COMPUTE
}

// ---------------------------------------------------------------- mvs = bf16(mv / dsum[m])   (k_dinv folded in)
__global__ __launch_bounds__(256) void k_mvs(
    const float* __restrict__ mval,   // [N][CV][M]
    const float* __restrict__ dsum,   // [N][M]
    uint16_t* __restrict__ mvs)       // [N][CV][M]
{
    unsigned i = blockIdx.x * 256 + threadIdx.x;
    unsigned base = i * 4u;
    unsigned n = base / (unsigned)(CV * M_);
    unsigned m = base % (unsigned)M_;
    floatx4 v = *(const floatx4*)&mval[base];
    floatx4 d = *(const floatx4*)&dsum[n * (unsigned)M_ + m];
    ushortx4 o;
    o[0] = f32_to_bf16(v[0] * (1.0f / d[0]));
    o[1] = f32_to_bf16(v[1] * (1.0f / d[1]));
    o[2] = f32_to_bf16(v[2] * (1.0f / d[2]));
    o[3] = f32_to_bf16(v[3] * (1.0f / d[3]));
    *(ushortx4*)&mvs[base] = o;
}

// ---------------------------------------------------------------- K2: out = mvs . E^T, no split, B-direct
// LDS-BW analysis (round-4 PMC): staged A+B = 48 KB LDS traffic per
// block-step = 741 cyc measured = the binding resource. Fix: B (E) fragments
// load STRAIGHT from global into registers (lane-addressable in E's native
// layout: 16 rows x 64B segments per instr, L2/L1-served); LDS carries only
// A (16 KB read + 8 KB DMA write per step ~ 350 cyc ~ MFMA 310 cyc).
// No split: grid 8qx4cx8n = 256 blocks = 1/CU, K=7200 accumulated in regs,
// out written directly (no partials, no reduce kernel).
// A: 3 LDS bufs, staged depth-2 via gload_lds (manual counted vmcnt — the
// DMA->ds_read dep is invisible to the compiler). B: 3 reg buffers, prefetch
// distance 1 (compiler tracks reg RAW waits itself).
// vmcnt ledger (A=2, B=4 instr/step): steady outstanding at iter entry =
// A(t)+A(t+1)+B(t) = 8; WAITV(6) drains exactly A(t) (oldest 2).
#define K2_NT 225   // 7200 / 32

__global__ __launch_bounds__(256) void k2_direct(
    const uint16_t* __restrict__ mvs,  // [N][CV][M] bf16 (already / dsum)
    const uint16_t* __restrict__ E,    // [N][HW][M] bf16
    float* __restrict__ out)           // [N][2CV][HW]; writes mapped half
{
    __shared__ __align__(16) short ldsA[3 * 4096];   // 3 bufs x [128 c][32 m]

    // grid 256: swizzle -> 32 consecutive ids per XCD = one full n-plane.
    const int bid = blockIdx.x + 8 * (blockIdx.y + 4 * blockIdx.z);
    const int swz = (bid & 7) * 32 + (bid >> 3);
    const int q0 = (swz & 7) << 7;
    const int c0 = ((swz >> 3) & 3) << 7;
    const int n  = swz >> 5;

    const int tid  = threadIdx.x;
    const int lane = tid & 63;
    const int wid  = tid >> 6;
    const int wc   = (wid >> 1) << 6;
    const int wq   = (wid & 1) << 6;
    const int fr   = lane & 15;
    const int quad = lane >> 4;

    // A staging: wave owns 2 chunks (16 rows x 32 cols each)
    const int ca = wid * 2;
    const int rr = lane >> 2;
    const int cc = (lane & 3) * 8;
    const uint16_t* A0p = mvs + (size_t)(n * CV + c0 + ca * 16 + rr) * M_ + cc;
    const uint16_t* A1p = A0p + (size_t)16 * M_;

    // B direct: lane (fr,quad) reads 16B at E[q0+wq+t*16+fr][m + quad*8].
    // Padded q rows (q0+..>=900) read garbage that stays inside the
    // workspace (max offset 105.5MB < 207MB); poisoned acc columns are
    // never written (gq<HW guard).
    const uint16_t* En = E + (size_t)n * HW * M_;
    const uint16_t* Bp0 = En + (size_t)(q0 + wq +  0 + fr) * M_ + quad * 8;
    const uint16_t* Bp1 = En + (size_t)(q0 + wq + 16 + fr) * M_ + quad * 8;
    const uint16_t* Bp2 = En + (size_t)(q0 + wq + 32 + fr) * M_ + quad * 8;
    const uint16_t* Bp3 = En + (size_t)(q0 + wq + 48 + fr) * M_ + quad * 8;

    floatx4 acc[4][4];
#pragma unroll
    for (int a = 0; a < 4; a++)
#pragma unroll
        for (int b = 0; b < 4; b++) acc[a][b] = (floatx4){0.f, 0.f, 0.f, 0.f};

    short8 breg[3][4];   // all indices compile-time (rule #20)

#define K2_STAGE_A(buf, mo) do { \
    gload_lds16(A0p + (mo), ldsA + (buf) * 4096 + ca * 512); \
    gload_lds16(A1p + (mo), ldsA + (buf) * 4096 + ca * 512 + 512); \
} while (0)

#define K2_LOAD_B(r, mo) do { \
    breg[r][0] = *(const short8*)(Bp0 + (mo)); \
    breg[r][1] = *(const short8*)(Bp1 + (mo)); \
    breg[r][2] = *(const short8*)(Bp2 + (mo)); \
    breg[r][3] = *(const short8*)(Bp3 + (mo)); \
} while (0)

#define K2_COMPUTE(bA, rC) do { \
    const short* pA = ldsA + (bA) * 4096; \
    short8 af[4]; \
    _Pragma("unroll") \
    for (int t = 0; t < 4; t++) \
        af[t] = *(const short8*)&pA[(wc + t * 16 + fr) * 32 + quad * 8]; \
    _Pragma("unroll") \
    for (int tc = 0; tc < 4; tc++) \
        _Pragma("unroll") \
        for (int tq = 0; tq < 4; tq++) \
            acc[tc][tq] = __builtin_amdgcn_mfma_f32_16x16x32_bf16( \
                af[tc], breg[rC][tq], acc[tc][tq], 0, 0, 0); \
} while (0)

    // prologue: A(0)->buf0, B(0)->breg0, A(1)->buf1   (8 outstanding)
    K2_STAGE_A(0, 0);
    K2_LOAD_B(0, 0);
    K2_STAGE_A(1, 32);

    int ao = 64;   // iter t stages A at (t+2)*32
    int bo = 32;   // iter t loads  B at (t+1)*32
    for (int s = 0; s < 74; s++) {        // t = 3s..3s+2  (0..221)
        WAITV(6); BARRIER();
        K2_STAGE_A(2, ao); K2_LOAD_B(1, bo); K2_COMPUTE(0, 0);
        ao += 32; bo += 32;
        WAITV(6); BARRIER();
        K2_STAGE_A(0, ao); K2_LOAD_B(2, bo); K2_COMPUTE(1, 1);
        ao += 32; bo += 32;
        WAITV(6); BARRIER();
        K2_STAGE_A(1, ao); K2_LOAD_B(0, bo); K2_COMPUTE(2, 2);
        ao += 32; bo += 32;
    }
    // t=222: stage A224->buf2, load B223->breg1, compute buf0/breg0
    WAITV(6); BARRIER();
    K2_STAGE_A(2, ao); K2_LOAD_B(1, bo); K2_COMPUTE(0, 0);
    bo += 32;
    // t=223
    WAITV(6); BARRIER();
    K2_LOAD_B(2, bo); K2_COMPUTE(1, 1);
    // t=224
    WAITV(4); BARRIER();
    K2_COMPUTE(2, 2);

    // epilogue: direct fp32 store to out (mapped half)
    float* On = out + (size_t)n * (2 * CV * HW) + (size_t)CV * HW;
#pragma unroll
    for (int tc = 0; tc < 4; tc++) {
#pragma unroll
        for (int tq = 0; tq < 4; tq++) {
            const int gq = q0 + wq + tq * 16 + fr;
            if (gq < HW) {
#pragma unroll
                for (int i = 0; i < 4; i++) {
                    const int gc = c0 + wc + tc * 16 + quad * 4 + i;
                    On[(size_t)gc * HW + gq] = acc[tc][tq][i];
                }
            }
        }
    }
#undef K2_STAGE_A
#undef K2_LOAD_B
#undef K2_COMPUTE
}

// ----------------------------------------------------------------
extern "C" void kernel_launch(void* const* d_in, const int* in_sizes, int n_in,
                              void* d_out, int out_size, void* d_ws, size_t ws_size,
                              hipStream_t stream) {
    const float* qkey = (const float*)d_in[0];  // [8][128][900]
    const float* qval = (const float*)d_in[1];  // [8][512][900]
    const float* mkey = (const float*)d_in[2];  // [8][128][7200]
    const float* mval = (const float*)d_in[3];  // [8][512][7200]
    float* out = (float*)d_out;                 // [8][1024][900]

    char* ws = (char*)d_ws;
    // E 103,680,000 | dsum 230,400 | (gap) | mvs 58,982,400 | qkT/mkT in old
    // partials region (layout kept from prior rounds; ws >= 207,360,000).
    uint16_t* E        = (uint16_t*)ws;
    float*    dsum     = (float*)(ws + 103680000);
    uint16_t* mvs      = (uint16_t*)(ws + 104140800);
    uint16_t* qkT      = (uint16_t*)(ws + 163123200);
    uint16_t* mkT      = (uint16_t*)(ws + 163123200 + 1843200);

    (void)in_sizes; (void)n_in; (void)out_size; (void)ws_size;

    k_zero<<<dim3((N_ * M_ + 255) / 256), 256, 0, stream>>>(dsum);
    k_copy_qval<<<dim3((N_ * CV * HW) / 4 / 256), 256, 0, stream>>>(qval, out);
    k_trans<<<dim3(29, 4, N_), 256, 0, stream>>>(qkey, qkT, HW);
    k_trans<<<dim3(225, 4, N_), 256, 0, stream>>>(mkey, mkT, M_);
    k1_gemm_exp<<<dim3(57, 8, N_), 256, 0, stream>>>(qkT, mkT, E, dsum);
    k_mvs<<<dim3((N_ * CV * M_) / 4 / 256), 256, 0, stream>>>(mval, dsum, mvs);
    k2_direct<<<dim3(8, 4, 8), 256, 0, stream>>>(mvs, E, out);
}

// Round 6
// 471.901 us; speedup vs baseline: 1.0375x; 1.0375x over previous
//
#include <hip/hip_runtime.h>
#include <stdint.h>

#define N_  8
#define CK  128
#define CV  512
#define HW  900     // 30*30 queries
#define M_  7200    // 8*30*30 memory slots
#define QK_SCALE 0.08838834764831845f  // 1/sqrt(128)

typedef __attribute__((ext_vector_type(8))) short  short8;
typedef __attribute__((ext_vector_type(4))) float  floatx4;
typedef __attribute__((ext_vector_type(4))) unsigned int   uintx4;
typedef __attribute__((ext_vector_type(4))) unsigned short ushortx4;

__device__ __forceinline__ uint16_t f32_to_bf16(float x) {
    union { float f; uint32_t u; } v; v.f = x;
    return (uint16_t)((v.u + 0x7FFFu + ((v.u >> 16) & 1u)) >> 16);
}

// Direct HBM -> LDS DMA, 16 B per lane. LDS dest is wave-uniform base
// (hardware adds lane*16B); global src is per-lane.
__device__ __forceinline__ void gload_lds16(const uint16_t* g, short* l) {
    __builtin_amdgcn_global_load_lds(
        (const __attribute__((address_space(1))) void*)g,
        (__attribute__((address_space(3))) void*)l,
        16, 0, 0);
}

// counted-vmcnt wait: loads stay in flight across barriers (T4)
#define WAITV(n) asm volatile("s_waitcnt vmcnt(" #n ")" ::: "memory")
// full fence barrier: sched_barrier on BOTH sides so no memory op (incl.
// global_load_lds) migrates across the s_barrier (m152 race class).
#define BARRIER() do { __builtin_amdgcn_sched_barrier(0); \
                       __builtin_amdgcn_s_barrier(); \
                       __builtin_amdgcn_sched_barrier(0); } while (0)

// ---------------------------------------------------------------- zero dsum
__global__ void k_zero(float* __restrict__ p) {
    int i = blockIdx.x * 256 + threadIdx.x;
    if (i < N_ * M_) p[i] = 0.f;
}

// ---------------------------------------------------------------- q_val copy (channels 0..511)
__global__ __launch_bounds__(256) void k_copy_qval(const float* __restrict__ qv,
                                                   float* __restrict__ out) {
    unsigned i = blockIdx.x * 256 + threadIdx.x;
    unsigned e = i * 4u;
    unsigned n = e / (CV * HW);
    unsigned off = e - n * (CV * HW);
    *(floatx4*)&out[(size_t)n * (2 * CV * HW) + off] = *(const floatx4*)&qv[e];
}

// ---------------------------------------------------------------- transpose [N][CK][L] fp32 -> [N][L][CK] bf16
__global__ __launch_bounds__(256) void k_trans(const float* __restrict__ in,
                                               uint16_t* __restrict__ outp, int L) {
    __shared__ float tile[32][33];
    const int tx = threadIdx.x & 31;
    const int ty = threadIdx.x >> 5;      // 0..7
    const int l0 = blockIdx.x * 32;
    const int c0 = blockIdx.y * 32;
    const int n  = blockIdx.z;
    const float* src = in + (size_t)n * CK * L;
    uint16_t* dst = outp + (size_t)n * L * CK;
#pragma unroll
    for (int p = 0; p < 4; p++) {
        int c = c0 + p * 8 + ty;
        int l = l0 + tx;
        float v = 0.f;
        if (l < L) v = src[(size_t)c * L + l];
        tile[p * 8 + ty][tx] = v;
    }
    __syncthreads();
#pragma unroll
    for (int p = 0; p < 4; p++) {
        int l = l0 + p * 8 + ty;
        int c = c0 + tx;
        if (l < L) dst[(size_t)l * CK + c] = f32_to_bf16(tile[tx][p * 8 + ty]);
    }
}

// ---------------------------------------------------------------- K1: aff = qkT mkT^T, exp, colsum
// Counted-vmcnt 4-buffer pipeline (BK=32, prefetch depth 3) — round-4 verbatim (passing, 139-era).
#define K1_TS 144   // C-tile stride (shorts)

__global__ __launch_bounds__(256) void k1_gemm_exp(
    const uint16_t* __restrict__ qkT,  // [N][HW][CK] bf16 (A: rows q, k=c)
    const uint16_t* __restrict__ mkT,  // [N][M][CK] bf16  (B: rows m, k=c)
    uint16_t* __restrict__ E,          // [N][HW][M] bf16 = exp(aff*scale)
    float* __restrict__ dsum)          // [N][M]
{
    __shared__ __align__(16) short smem[32768];   // 4 bufs x (A 4096 + B 4096)
    __shared__ float colsum[128];

    // XCD swizzle: 3648 blocks, 456/XCD = exactly one n-plane per XCD.
    const int bid = blockIdx.x + 57 * (blockIdx.y + 8 * blockIdx.z);
    const int swz = (bid & 7) * 456 + (bid >> 3);
    const int mb   = swz % 57;
    const int rest = swz / 57;
    const int m0 = mb * 128;
    const int q0 = (rest & 7) * 128;
    const int n  = rest >> 3;
    const int tid = threadIdx.x;

    if (tid < 128) colsum[tid] = 0.f;

    const int lane = tid & 63;
    const int wid  = tid >> 6;
    const int wq   = (wid >> 1) << 6;
    const int wm   = (wid & 1) << 6;
    const int fr   = lane & 15;
    const int quad = lane >> 4;

    const int ca = wid * 2;
    const int rr = lane >> 2;        // row within chunk 0..15
    const int cc = (lane & 3) * 8;   // col (shorts), 16B aligned

    const uint16_t* Ab = qkT + (size_t)n * HW * CK;
    const uint16_t* Bb = mkT + (size_t)n * M_ * CK;
    const uint16_t* A0p = Ab + (size_t)(q0 + ca * 16 + rr) * CK + cc;
    const uint16_t* A1p = A0p + 16 * CK;
    const uint16_t* B0p = Bb + (size_t)(m0 + ca * 16 + rr) * CK + cc;
    const uint16_t* B1p = B0p + 16 * CK;

    floatx4 acc[4][4];
#pragma unroll
    for (int a = 0; a < 4; a++)
#pragma unroll
        for (int b = 0; b < 4; b++) acc[a][b] = (floatx4){0.f, 0.f, 0.f, 0.f};

#define K1_STAGE(buf, ko) do { \
    short* dA = smem + (buf) * 8192 + ca * 512; \
    short* dB = dA + 4096; \
    gload_lds16(A0p + (ko), dA); \
    gload_lds16(A1p + (ko), dA + 512); \
    gload_lds16(B0p + (ko), dB); \
    gload_lds16(B1p + (ko), dB + 512); \
} while (0)

#define K1_COMPUTE(buf) do { \
    const short* bA = smem + (buf) * 8192; \
    const short* bB = bA + 4096; \
    const int k0 = quad * 8; \
    short8 af[4], bfr[4]; \
    _Pragma("unroll") \
    for (int t = 0; t < 4; t++) \
        af[t] = *(const short8*)&bA[(wq + t * 16 + fr) * 32 + k0]; \
    _Pragma("unroll") \
    for (int t = 0; t < 4; t++) \
        bfr[t] = *(const short8*)&bB[(wm + t * 16 + fr) * 32 + k0]; \
    _Pragma("unroll") \
    for (int tq = 0; tq < 4; tq++) \
        _Pragma("unroll") \
        for (int tm = 0; tm < 4; tm++) \
            acc[tq][tm] = __builtin_amdgcn_mfma_f32_16x16x32_bf16( \
                af[tq], bfr[tm], acc[tq][tm], 0, 0, 0); \
} while (0)

    // prefetch depth 3 over 4 K-steps (CK=128, BK=32)
    K1_STAGE(0, 0); K1_STAGE(1, 32); K1_STAGE(2, 64);
    WAITV(8); BARRIER(); K1_STAGE(3, 96); K1_COMPUTE(0);   // t=0
    WAITV(8); BARRIER(); K1_COMPUTE(1);                    // t=1
    WAITV(4); BARRIER(); K1_COMPUTE(2);                    // t=2
    WAITV(0); BARRIER(); K1_COMPUTE(3);                    // t=3

    // ---- epilogue phase A: exp -> LDS C-tile (stride 144), colsum
    __syncthreads();   // all frag reads done; smem reusable as C-tile
    float cs[4] = {0.f, 0.f, 0.f, 0.f};
#pragma unroll
    for (int tq = 0; tq < 4; tq++) {
#pragma unroll
        for (int tm = 0; tm < 4; tm++) {
            const int col = wm + tm * 16 + fr;
#pragma unroll
            for (int i = 0; i < 4; i++) {
                const int row = wq + tq * 16 + quad * 4 + i;
                float e = __expf(acc[tq][tm][i] * QK_SCALE);
                if (q0 + row < HW) cs[tm] += e;   // guard: padded q-rows must not pollute colsum
                smem[row * K1_TS + col] = (short)f32_to_bf16(e);
            }
        }
    }
#pragma unroll
    for (int tm = 0; tm < 4; tm++) {
        float s = cs[tm];
        s += __shfl_xor(s, 16, 64);
        s += __shfl_xor(s, 32, 64);
        if (quad == 0) atomicAdd(&colsum[wm + tm * 16 + fr], s);
    }
    __syncthreads();   // C-tile complete + colsum complete

    // ---- epilogue phase B: coalesced uint4 E-writes (8 per thread)
    uint16_t* En = E + (size_t)n * HW * M_;
#pragma unroll
    for (int j = 0; j < 8; j++) {
        int idx = tid + j * 256;       // 0..2047 = 128 rows x 16 uint4
        int r   = idx >> 4;
        int c8  = (idx & 15) * 8;      // short offset in row
        if (q0 + r < HW && m0 + c8 + 8 <= M_) {
            uintx4 v = *(const uintx4*)&smem[r * K1_TS + c8];
            *(uintx4*)&En[(size_t)(q0 + r) * M_ + m0 + c8] = v;
        }
    }
    if (tid < 128) {
        const int gm = m0 + tid;
        if (gm < M_) atomicAdd(&dsum[(size_t)n * M_ + gm], colsum[tid]);
    }
#undef K1_STAGE
#undef K1_COMPUTE
}

// ---------------------------------------------------------------- mvs = bf16(mv / dsum[m])
__global__ __launch_bounds__(256) void k_mvs(
    const float* __restrict__ mval,   // [N][CV][M]
    const float* __restrict__ dsum,   // [N][M]
    uint16_t* __restrict__ mvs)       // [N][CV][M]
{
    unsigned i = blockIdx.x * 256 + threadIdx.x;
    unsigned base = i * 4u;
    unsigned n = base / (unsigned)(CV * M_);
    unsigned m = base % (unsigned)M_;
    floatx4 v = *(const floatx4*)&mval[base];
    floatx4 d = *(const floatx4*)&dsum[n * (unsigned)M_ + m];
    ushortx4 o;
    o[0] = f32_to_bf16(v[0] * (1.0f / d[0]));
    o[1] = f32_to_bf16(v[1] * (1.0f / d[1]));
    o[2] = f32_to_bf16(v[2] * (1.0f / d[2]));
    o[3] = f32_to_bf16(v[3] * (1.0f / d[3]));
    *(ushortx4*)&mvs[base] = o;
}

// ---------------------------------------------------------------- K2 hybrid: out = mvs . E^T
// Evidence: r1/r4 both ~139us with equal total LDS bytes -> LDS-BW-bound
// (~66 B/cyc realized incl. DMA writes). Fix: B (E) never touches LDS —
// global->reg at PREFETCH DEPTH 2 (r5's depth-1 made the compiler's
// auto-wait before MFMA a vmcnt(0) full drain = 2420 cyc/step; depth 2
// makes it vmcnt(12), leaving 2 step-times of latency cover). A stays
// DMA->LDS (3-buf ring, 8KB/buf). LDS/block-step: 24KB (was 48).
// No K-split: K=7200 in regs, out written directly (no partials/reduce3).
// vmcnt ledger: prologue A0,B0,A1,B1 = 12 outstanding. Steady iter t:
// WAITV(10) [newest 10 = B(t),A(t+1),B(t+1) -> A(t) landed]; BARRIER;
// STAGE_A(t+2); LOAD_B(t+2); COMPUTE(t). Compiler's breg(t) wait = vmcnt(12).
#define K2_NT 225   // 7200 / 32

__global__ __launch_bounds__(256) void k2_hyb(
    const uint16_t* __restrict__ mvs,  // [N][CV][M] bf16 (already / dsum)
    const uint16_t* __restrict__ E,    // [N][HW][M] bf16
    float* __restrict__ out)           // [N][2CV][HW]; writes mapped half
{
    __shared__ __align__(16) short ldsA[3 * 4096];   // 3 bufs x [128 c][32 m]

    // swizzle: 32 consecutive ids per XCD = one full n-plane; c0 FASTEST so
    // the 4 c-blocks sharing a q0's E rows run adjacently (E L2-reuse x4);
    // all 256 blocks stream m in near-lockstep -> moving-window L2 reuse.
    const int bid = blockIdx.x + 8 * (blockIdx.y + 4 * blockIdx.z);
    const int swz = (bid & 7) * 32 + (bid >> 3);
    const int c0 = (swz & 3) << 7;
    const int q0 = ((swz >> 2) & 7) << 7;
    const int n  = swz >> 5;

    const int tid  = threadIdx.x;
    const int lane = tid & 63;
    const int wid  = tid >> 6;
    const int wc   = (wid >> 1) << 6;
    const int wq   = (wid & 1) << 6;
    const int fr   = lane & 15;
    const int quad = lane >> 4;

    // A staging: 8 chunks of 1KB (16 rows x 32 cols); wave owns 2 chunks.
    const int ca = wid * 2;
    const int rr = lane >> 2;
    const int cc = (lane & 3) * 8;
    const uint16_t* A0p = mvs + (size_t)(n * CV + c0 + ca * 16 + rr) * M_ + cc;
    const uint16_t* A1p = A0p + (size_t)16 * M_;

    // B direct: lane (fr,quad) reads 16B at E[q0+wq+t*16+fr][m + quad*8].
    // Padded q rows (>=900) read garbage inside the workspace; poisoned acc
    // columns are never written (gq<HW guard). (Correctness proven r5.)
    const uint16_t* En = E + (size_t)n * HW * M_;
    const uint16_t* Bp0 = En + (size_t)(q0 + wq +  0 + fr) * M_ + quad * 8;
    const uint16_t* Bp1 = En + (size_t)(q0 + wq + 16 + fr) * M_ + quad * 8;
    const uint16_t* Bp2 = En + (size_t)(q0 + wq + 32 + fr) * M_ + quad * 8;
    const uint16_t* Bp3 = En + (size_t)(q0 + wq + 48 + fr) * M_ + quad * 8;

    floatx4 acc[4][4];
#pragma unroll
    for (int a = 0; a < 4; a++)
#pragma unroll
        for (int b = 0; b < 4; b++) acc[a][b] = (floatx4){0.f, 0.f, 0.f, 0.f};

    short8 breg0[4], breg1[4], breg2[4];   // static ring (rule #20)

#define K2_STAGE_A(buf, mo) do { \
    gload_lds16(A0p + (mo), ldsA + (buf) * 4096 + ca * 512); \
    gload_lds16(A1p + (mo), ldsA + (buf) * 4096 + ca * 512 + 512); \
} while (0)

#define K2_LOAD_B(brg, mo) do { \
    brg[0] = *(const short8*)(Bp0 + (mo)); \
    brg[1] = *(const short8*)(Bp1 + (mo)); \
    brg[2] = *(const short8*)(Bp2 + (mo)); \
    brg[3] = *(const short8*)(Bp3 + (mo)); \
} while (0)

#define K2_COMPUTE(bA, brg) do { \
    const short* pA = ldsA + (bA) * 4096; \
    short8 af[4]; \
    _Pragma("unroll") \
    for (int t = 0; t < 4; t++) \
        af[t] = *(const short8*)&pA[(wc + t * 16 + fr) * 32 + quad * 8]; \
    _Pragma("unroll") \
    for (int tc = 0; tc < 4; tc++) \
        _Pragma("unroll") \
        for (int tq = 0; tq < 4; tq++) \
            acc[tc][tq] = __builtin_amdgcn_mfma_f32_16x16x32_bf16( \
                af[tc], brg[tq], acc[tc][tq], 0, 0, 0); \
} while (0)

    // prologue: depth-2 on BOTH operands (12 outstanding)
    K2_STAGE_A(0, 0);  K2_LOAD_B(breg0, 0);
    K2_STAGE_A(1, 32); K2_LOAD_B(breg1, 32);

    int mo = 64;   // iter t stages/loads at (t+2)*32
    for (int s = 0; s < 74; s++) {          // t = 3s..3s+2  (0..221)
        WAITV(10); BARRIER();
        K2_STAGE_A(2, mo); K2_LOAD_B(breg2, mo); K2_COMPUTE(0, breg0);
        mo += 32;
        WAITV(10); BARRIER();
        K2_STAGE_A(0, mo); K2_LOAD_B(breg0, mo); K2_COMPUTE(1, breg1);
        mo += 32;
        WAITV(10); BARRIER();
        K2_STAGE_A(1, mo); K2_LOAD_B(breg1, mo); K2_COMPUTE(2, breg2);
        mo += 32;
    }
    // t=222: stage/load 224 -> slot 2; compute 0
    WAITV(10); BARRIER();
    K2_STAGE_A(2, mo); K2_LOAD_B(breg2, mo); K2_COMPUTE(0, breg0);
    // t=223
    WAITV(10); BARRIER();
    K2_COMPUTE(1, breg1);
    // t=224
    WAITV(4); BARRIER();
    K2_COMPUTE(2, breg2);

    // epilogue: direct fp32 store to out (mapped half) — r5-verified mapping
    float* On = out + (size_t)n * (2 * CV * HW) + (size_t)CV * HW;
#pragma unroll
    for (int tc = 0; tc < 4; tc++) {
#pragma unroll
        for (int tq = 0; tq < 4; tq++) {
            const int gq = q0 + wq + tq * 16 + fr;
            if (gq < HW) {
#pragma unroll
                for (int i = 0; i < 4; i++) {
                    const int gc = c0 + wc + tc * 16 + quad * 4 + i;
                    On[(size_t)gc * HW + gq] = acc[tc][tq][i];
                }
            }
        }
    }
#undef K2_STAGE_A
#undef K2_LOAD_B
#undef K2_COMPUTE
}

// ----------------------------------------------------------------
extern "C" void kernel_launch(void* const* d_in, const int* in_sizes, int n_in,
                              void* d_out, int out_size, void* d_ws, size_t ws_size,
                              hipStream_t stream) {
    const float* qkey = (const float*)d_in[0];  // [8][128][900]
    const float* qval = (const float*)d_in[1];  // [8][512][900]
    const float* mkey = (const float*)d_in[2];  // [8][128][7200]
    const float* mval = (const float*)d_in[3];  // [8][512][7200]
    float* out = (float*)d_out;                 // [8][1024][900]

    char* ws = (char*)d_ws;
    // E 103,680,000 | dsum 230,400 | (gap) | mvs 58,982,400 | qkT/mkT high
    uint16_t* E        = (uint16_t*)ws;
    float*    dsum     = (float*)(ws + 103680000);
    uint16_t* mvs      = (uint16_t*)(ws + 104140800);
    uint16_t* qkT      = (uint16_t*)(ws + 163123200);
    uint16_t* mkT      = (uint16_t*)(ws + 163123200 + 1843200);

    (void)in_sizes; (void)n_in; (void)out_size; (void)ws_size;

    k_zero<<<dim3((N_ * M_ + 255) / 256), 256, 0, stream>>>(dsum);
    k_copy_qval<<<dim3((N_ * CV * HW) / 4 / 256), 256, 0, stream>>>(qval, out);
    k_trans<<<dim3(29, 4, N_), 256, 0, stream>>>(qkey, qkT, HW);
    k_trans<<<dim3(225, 4, N_), 256, 0, stream>>>(mkey, mkT, M_);
    k1_gemm_exp<<<dim3(57, 8, N_), 256, 0, stream>>>(qkT, mkT, E, dsum);
    k_mvs<<<dim3((N_ * CV * M_) / 4 / 256), 256, 0, stream>>>(mval, dsum, mvs);
    k2_hyb<<<dim3(8, 4, 8), 256, 0, stream>>>(mvs, E, out);
}

// Round 8
// 431.533 us; speedup vs baseline: 1.1346x; 1.0935x over previous
//
#include <hip/hip_runtime.h>
#include <stdint.h>

#define N_  8
#define CK  128
#define CV  512
#define HW  900     // 30*30 queries
#define M_  7200    // 8*30*30 memory slots
#define QK_SCALE 0.08838834764831845f  // 1/sqrt(128)

typedef __attribute__((ext_vector_type(8))) short  short8;
typedef __attribute__((ext_vector_type(4))) float  floatx4;
typedef __attribute__((ext_vector_type(4))) unsigned int   uintx4;
typedef __attribute__((ext_vector_type(4))) unsigned short ushortx4;

__device__ __forceinline__ uint16_t f32_to_bf16(float x) {
    union { float f; uint32_t u; } v; v.f = x;
    return (uint16_t)((v.u + 0x7FFFu + ((v.u >> 16) & 1u)) >> 16);
}

// Direct HBM -> LDS DMA, 16 B per lane. LDS dest is wave-uniform base
// (hardware adds lane*16B); global src is per-lane.
__device__ __forceinline__ void gload_lds16(const uint16_t* g, short* l) {
    __builtin_amdgcn_global_load_lds(
        (const __attribute__((address_space(1))) void*)g,
        (__attribute__((address_space(3))) void*)l,
        16, 0, 0);
}

// counted-vmcnt wait: loads stay in flight across barriers (T4)
#define WAITV(n) asm volatile("s_waitcnt vmcnt(" #n ")" ::: "memory")
// full fence barrier: sched_barrier on BOTH sides so no memory op (incl.
// global_load_lds) migrates across the s_barrier (m152 race class).
#define BARRIER() do { __builtin_amdgcn_sched_barrier(0); \
                       __builtin_amdgcn_s_barrier(); \
                       __builtin_amdgcn_sched_barrier(0); } while (0)

// ---------------------------------------------------------------- fused prep:
// [0,928)        transpose qkey -> qkT   (29 x 4 x 8 tiles, L=900)
// [928,8128)     transpose mkey -> mkT   (225 x 4 x 8 tiles, L=7200)
// [8128,11728)   copy q_val -> out first half (3600 blocks: N*CV*HW/4/256)
// [11728,11953)  zero dsum (225 blocks)
__device__ __forceinline__ void trans_body(const float* __restrict__ in,
                                           uint16_t* __restrict__ outp, int L,
                                           int bx, int by, int bz, int tid) {
    __shared__ float tile[32][33];
    const int tx = tid & 31;
    const int ty = tid >> 5;
    const int l0 = bx * 32;
    const int c0 = by * 32;
    const float* src = in + (size_t)bz * CK * L;
    uint16_t* dst = outp + (size_t)bz * L * CK;
#pragma unroll
    for (int p = 0; p < 4; p++) {
        int c = c0 + p * 8 + ty;
        int l = l0 + tx;
        float v = 0.f;
        if (l < L) v = src[(size_t)c * L + l];
        tile[p * 8 + ty][tx] = v;
    }
    __syncthreads();
#pragma unroll
    for (int p = 0; p < 4; p++) {
        int l = l0 + p * 8 + ty;
        int c = c0 + tx;
        if (l < L) dst[(size_t)l * CK + c] = f32_to_bf16(tile[tx][p * 8 + ty]);
    }
}

__global__ __launch_bounds__(256) void k_prep(
    const float* __restrict__ qkey, const float* __restrict__ mkey,
    const float* __restrict__ qval, float* __restrict__ out,
    uint16_t* __restrict__ qkT, uint16_t* __restrict__ mkT,
    float* __restrict__ dsum)
{
    const int b = blockIdx.x;
    const int tid = threadIdx.x;
    if (b < 928) {
        trans_body(qkey, qkT, HW, b % 29, (b / 29) & 3, b / 116, tid);
    } else if (b < 8128) {
        const int bb = b - 928;
        trans_body(mkey, mkT, M_, bb % 225, (bb / 225) & 3, bb / 900, tid);
    } else if (b < 11728) {
        const int bb = b - 8128;
        unsigned i = (unsigned)bb * 256 + tid;    // 0..921599
        unsigned e = i * 4u;                      // float index, < 3,686,400
        unsigned n = e / (CV * HW);
        unsigned off = e - n * (CV * HW);
        *(floatx4*)&out[(size_t)n * (2 * CV * HW) + off] = *(const floatx4*)&qval[e];
    } else {
        const int bb = b - 11728;
        int i = bb * 256 + tid;
        if (i < N_ * M_) dsum[i] = 0.f;
    }
}

// ---------------------------------------------------------------- K1: aff = qkT mkT^T, exp, colsum
// Counted-vmcnt 4-buffer pipeline (BK=32, depth 3) — round-4 verbatim (passing).
#define K1_TS 144   // C-tile stride (shorts)

__global__ __launch_bounds__(256) void k1_gemm_exp(
    const uint16_t* __restrict__ qkT,  // [N][HW][CK] bf16 (A: rows q, k=c)
    const uint16_t* __restrict__ mkT,  // [N][M][CK] bf16  (B: rows m, k=c)
    uint16_t* __restrict__ E,          // [N][HW][M] bf16 = exp(aff*scale)
    float* __restrict__ dsum)          // [N][M]
{
    __shared__ __align__(16) short smem[32768];   // 4 bufs x (A 4096 + B 4096)
    __shared__ float colsum[128];

    // XCD swizzle: 3648 blocks, 456/XCD = exactly one n-plane per XCD.
    const int bid = blockIdx.x + 57 * (blockIdx.y + 8 * blockIdx.z);
    const int swz = (bid & 7) * 456 + (bid >> 3);
    const int mb   = swz % 57;
    const int rest = swz / 57;
    const int m0 = mb * 128;
    const int q0 = (rest & 7) * 128;
    const int n  = rest >> 3;
    const int tid = threadIdx.x;

    if (tid < 128) colsum[tid] = 0.f;

    const int lane = tid & 63;
    const int wid  = tid >> 6;
    const int wq   = (wid >> 1) << 6;
    const int wm   = (wid & 1) << 6;
    const int fr   = lane & 15;
    const int quad = lane >> 4;

    const int ca = wid * 2;
    const int rr = lane >> 2;        // row within chunk 0..15
    const int cc = (lane & 3) * 8;   // col (shorts), 16B aligned

    const uint16_t* Ab = qkT + (size_t)n * HW * CK;
    const uint16_t* Bb = mkT + (size_t)n * M_ * CK;
    const uint16_t* A0p = Ab + (size_t)(q0 + ca * 16 + rr) * CK + cc;
    const uint16_t* A1p = A0p + 16 * CK;
    const uint16_t* B0p = Bb + (size_t)(m0 + ca * 16 + rr) * CK + cc;
    const uint16_t* B1p = B0p + 16 * CK;

    floatx4 acc[4][4];
#pragma unroll
    for (int a = 0; a < 4; a++)
#pragma unroll
        for (int b = 0; b < 4; b++) acc[a][b] = (floatx4){0.f, 0.f, 0.f, 0.f};

#define K1_STAGE(buf, ko) do { \
    short* dA = smem + (buf) * 8192 + ca * 512; \
    short* dB = dA + 4096; \
    gload_lds16(A0p + (ko), dA); \
    gload_lds16(A1p + (ko), dA + 512); \
    gload_lds16(B0p + (ko), dB); \
    gload_lds16(B1p + (ko), dB + 512); \
} while (0)

#define K1_COMPUTE(buf) do { \
    const short* bA = smem + (buf) * 8192; \
    const short* bB = bA + 4096; \
    const int k0 = quad * 8; \
    short8 af[4], bfr[4]; \
    _Pragma("unroll") \
    for (int t = 0; t < 4; t++) \
        af[t] = *(const short8*)&bA[(wq + t * 16 + fr) * 32 + k0]; \
    _Pragma("unroll") \
    for (int t = 0; t < 4; t++) \
        bfr[t] = *(const short8*)&bB[(wm + t * 16 + fr) * 32 + k0]; \
    _Pragma("unroll") \
    for (int tq = 0; tq < 4; tq++) \
        _Pragma("unroll") \
        for (int tm = 0; tm < 4; tm++) \
            acc[tq][tm] = __builtin_amdgcn_mfma_f32_16x16x32_bf16( \
                af[tq], bfr[tm], acc[tq][tm], 0, 0, 0); \
} while (0)

    // prefetch depth 3 over 4 K-steps (CK=128, BK=32)
    K1_STAGE(0, 0); K1_STAGE(1, 32); K1_STAGE(2, 64);
    WAITV(8); BARRIER(); K1_STAGE(3, 96); K1_COMPUTE(0);   // t=0
    WAITV(8); BARRIER(); K1_COMPUTE(1);                    // t=1
    WAITV(4); BARRIER(); K1_COMPUTE(2);                    // t=2
    WAITV(0); BARRIER(); K1_COMPUTE(3);                    // t=3

    // ---- epilogue phase A: exp -> LDS C-tile (stride 144), colsum
    __syncthreads();   // all frag reads done; smem reusable as C-tile
    float cs[4] = {0.f, 0.f, 0.f, 0.f};
#pragma unroll
    for (int tq = 0; tq < 4; tq++) {
#pragma unroll
        for (int tm = 0; tm < 4; tm++) {
            const int col = wm + tm * 16 + fr;
#pragma unroll
            for (int i = 0; i < 4; i++) {
                const int row = wq + tq * 16 + quad * 4 + i;
                float e = __expf(acc[tq][tm][i] * QK_SCALE);
                if (q0 + row < HW) cs[tm] += e;   // guard: padded q-rows must not pollute colsum
                smem[row * K1_TS + col] = (short)f32_to_bf16(e);
            }
        }
    }
#pragma unroll
    for (int tm = 0; tm < 4; tm++) {
        float s = cs[tm];
        s += __shfl_xor(s, 16, 64);
        s += __shfl_xor(s, 32, 64);
        if (quad == 0) atomicAdd(&colsum[wm + tm * 16 + fr], s);
    }
    __syncthreads();   // C-tile complete + colsum complete

    // ---- epilogue phase B: coalesced uint4 E-writes (8 per thread)
    uint16_t* En = E + (size_t)n * HW * M_;
#pragma unroll
    for (int j = 0; j < 8; j++) {
        int idx = tid + j * 256;       // 0..2047 = 128 rows x 16 uint4
        int r   = idx >> 4;
        int c8  = (idx & 15) * 8;      // short offset in row
        if (q0 + r < HW && m0 + c8 + 8 <= M_) {
            uintx4 v = *(const uintx4*)&smem[r * K1_TS + c8];
            *(uintx4*)&En[(size_t)(q0 + r) * M_ + m0 + c8] = v;
        }
    }
    if (tid < 128) {
        const int gm = m0 + tid;
        if (gm < M_) atomicAdd(&dsum[(size_t)n * M_ + gm], colsum[tid]);
    }
#undef K1_STAGE
#undef K1_COMPUTE
}

// ---------------------------------------------------------------- mvs = bf16(mv / dsum[m])
__global__ __launch_bounds__(256) void k_mvs(
    const float* __restrict__ mval,   // [N][CV][M]
    const float* __restrict__ dsum,   // [N][M]
    uint16_t* __restrict__ mvs)       // [N][CV][M]
{
    unsigned i = blockIdx.x * 256 + threadIdx.x;
    unsigned base = i * 4u;
    unsigned n = base / (unsigned)(CV * M_);
    unsigned m = base % (unsigned)M_;
    floatx4 v = *(const floatx4*)&mval[base];
    floatx4 d = *(const floatx4*)&dsum[n * (unsigned)M_ + m];
    ushortx4 o;
    o[0] = f32_to_bf16(v[0] * (1.0f / d[0]));
    o[1] = f32_to_bf16(v[1] * (1.0f / d[1]));
    o[2] = f32_to_bf16(v[2] * (1.0f / d[2]));
    o[3] = f32_to_bf16(v[3] * (1.0f / d[3]));
    *(ushortx4*)&mvs[base] = o;
}

// ---------------------------------------------------------------- K2 split x3, B-in-registers
// Single-variable redo of r5/r6: B-in-regs (E never touches LDS) but WITH
// split3 restored -> 768 blocks = 3/CU co-resident (r5/r6 died at 1 block/CU:
// barrier-lockstep waves with zero cross-block overlap expose all latency).
// LDS/block-step: 24 KB (A-ring only) vs 48 KB staged-both (r1/r4 @139us).
// vmcnt ledger/iter t: enter 12 out [A(t),B(t),A(t+1),B(t+1)]; WAITV(10)
// drains A(t); BARRIER; stage A(t+2)+load B(t+2) -> 16; compiler's wait for
// breg(t) = vmcnt(12) (B(t) is 2 steps old). Tail: WAITV(10)/WAITV(4).
#define K2_SPLITS 3
#define K2_BK 32
#define K2_STEPS 75   // 2400 / 32

__global__ __launch_bounds__(256, 3) void k2_split3b(
    const uint16_t* __restrict__ mvs,  // [N][CV][M] bf16 (already / dsum)
    const uint16_t* __restrict__ E,    // [N][HW][M] bf16
    float* __restrict__ partials)      // [3][N][CV][HW]
{
    __shared__ __align__(16) short ldsA[3 * 4096];   // 3 bufs x [128 c][32 m]

    // XCD swizzle: 768 blocks, 96/XCD = one n-plane (3 splits) per XCD.
    // c0 fastest: 4 c-blocks sharing a q0's E rows run adjacently (L2 x4).
    const int bid = blockIdx.x + 8 * (blockIdx.y + 4 * blockIdx.z);
    const int swz = (bid & 7) * 96 + (bid >> 3);
    const int c0 = (swz & 3) << 7;
    const int q0 = ((swz >> 2) & 7) << 7;
    const int nz = swz >> 5;
    const int n     = nz / K2_SPLITS;
    const int split = nz - n * K2_SPLITS;

    const int tid  = threadIdx.x;
    const int lane = tid & 63;
    const int wid  = tid >> 6;
    const int wc   = (wid >> 1) << 6;
    const int wq   = (wid & 1) << 6;
    const int fr   = lane & 15;
    const int quad = lane >> 4;

    // A staging: 8 chunks of 1KB (16 rows x 32 cols); wave owns 2 chunks.
    const int ca = wid * 2;
    const int rr = lane >> 2;
    const int cc = (lane & 3) * 8;
    const uint16_t* A0p = mvs + (size_t)(n * CV + c0 + ca * 16 + rr) * M_
                              + split * 2400 + cc;
    const uint16_t* A1p = A0p + (size_t)16 * M_;

    // B direct: lane (fr,quad) reads 16B at E[q0+wq+t*16+fr][m + quad*8].
    // Padded q rows (>=900) read garbage inside the workspace (max read
    // ~105 MB < 207 MB); poisoned acc columns never written (gq<HW guard).
    const uint16_t* En = E + (size_t)n * HW * M_ + split * 2400;
    const uint16_t* Bp0 = En + (size_t)(q0 + wq +  0 + fr) * M_ + quad * 8;
    const uint16_t* Bp1 = En + (size_t)(q0 + wq + 16 + fr) * M_ + quad * 8;
    const uint16_t* Bp2 = En + (size_t)(q0 + wq + 32 + fr) * M_ + quad * 8;
    const uint16_t* Bp3 = En + (size_t)(q0 + wq + 48 + fr) * M_ + quad * 8;

    floatx4 acc[4][4];
#pragma unroll
    for (int a = 0; a < 4; a++)
#pragma unroll
        for (int b = 0; b < 4; b++) acc[a][b] = (floatx4){0.f, 0.f, 0.f, 0.f};

    short8 breg0[4], breg1[4], breg2[4];   // static ring (rule #20)

#define K2_STAGE_A(buf, mo) do { \
    gload_lds16(A0p + (mo), ldsA + (buf) * 4096 + ca * 512); \
    gload_lds16(A1p + (mo), ldsA + (buf) * 4096 + ca * 512 + 512); \
} while (0)

#define K2_LOAD_B(brg, mo) do { \
    brg[0] = *(const short8*)(Bp0 + (mo)); \
    brg[1] = *(const short8*)(Bp1 + (mo)); \
    brg[2] = *(const short8*)(Bp2 + (mo)); \
    brg[3] = *(const short8*)(Bp3 + (mo)); \
} while (0)

#define K2_COMPUTE(bA, brg) do { \
    const short* pA = ldsA + (bA) * 4096; \
    short8 af[4]; \
    _Pragma("unroll") \
    for (int t = 0; t < 4; t++) \
        af[t] = *(const short8*)&pA[(wc + t * 16 + fr) * 32 + quad * 8]; \
    _Pragma("unroll") \
    for (int tc = 0; tc < 4; tc++) \
        _Pragma("unroll") \
        for (int tq = 0; tq < 4; tq++) \
            acc[tc][tq] = __builtin_amdgcn_mfma_f32_16x16x32_bf16( \
                af[tc], brg[tq], acc[tc][tq], 0, 0, 0); \
} while (0)

    // prologue: depth-2 on BOTH operands (12 outstanding)
    K2_STAGE_A(0, 0);  K2_LOAD_B(breg0, 0);
    K2_STAGE_A(1, 32); K2_LOAD_B(breg1, 32);

    int mo = 64;   // iter t stages/loads at (t+2)*32
    for (int s = 0; s < 24; s++) {          // t = 3s..3s+2  (0..71)
        WAITV(10); BARRIER();
        K2_STAGE_A(2, mo); K2_LOAD_B(breg2, mo); K2_COMPUTE(0, breg0);
        mo += 32;
        WAITV(10); BARRIER();
        K2_STAGE_A(0, mo); K2_LOAD_B(breg0, mo); K2_COMPUTE(1, breg1);
        mo += 32;
        WAITV(10); BARRIER();
        K2_STAGE_A(1, mo); K2_LOAD_B(breg1, mo); K2_COMPUTE(2, breg2);
        mo += 32;
    }
    // t=72: stage/load m-step 74 -> slot 2; compute 0
    WAITV(10); BARRIER();
    K2_STAGE_A(2, mo); K2_LOAD_B(breg2, mo); K2_COMPUTE(0, breg0);
    // t=73
    WAITV(10); BARRIER();
    K2_COMPUTE(1, breg1);
    // t=74
    WAITV(4); BARRIER();
    K2_COMPUTE(2, breg2);

    // epilogue: store partials (r4-verified mapping)
    float* P = partials + ((size_t)split * N_ + n) * CV * HW;
#pragma unroll
    for (int tc = 0; tc < 4; tc++) {
#pragma unroll
        for (int tq = 0; tq < 4; tq++) {
            const int gq = q0 + wq + tq * 16 + fr;
            if (gq < HW) {
#pragma unroll
                for (int i = 0; i < 4; i++) {
                    const int gc = c0 + wc + tc * 16 + quad * 4 + i;
                    P[(size_t)gc * HW + gq] = acc[tc][tq][i];
                }
            }
        }
    }
#undef K2_STAGE_A
#undef K2_LOAD_B
#undef K2_COMPUTE
}

// ---------------------------------------------------------------- reduce 3 partials -> out mapped half
__global__ __launch_bounds__(256) void k_reduce3(const float* __restrict__ partials,
                                                 float* __restrict__ out) {
    unsigned i = blockIdx.x * 256 + threadIdx.x;
    unsigned e = i * 4u;
    unsigned n = e / (CV * HW);
    unsigned off = e - n * (CV * HW);
    const size_t stride = (size_t)N_ * CV * HW;
    const float* p = partials + (size_t)n * CV * HW + off;
    floatx4 a = *(const floatx4*)&p[0];
    floatx4 b = *(const floatx4*)&p[stride];
    floatx4 c = *(const floatx4*)&p[2 * stride];
    floatx4 s = a + b + c;
    *(floatx4*)&out[(size_t)n * (2 * CV * HW) + CV * HW + off] = s;
}

// ----------------------------------------------------------------
extern "C" void kernel_launch(void* const* d_in, const int* in_sizes, int n_in,
                              void* d_out, int out_size, void* d_ws, size_t ws_size,
                              hipStream_t stream) {
    const float* qkey = (const float*)d_in[0];  // [8][128][900]
    const float* qval = (const float*)d_in[1];  // [8][512][900]
    const float* mkey = (const float*)d_in[2];  // [8][128][7200]
    const float* mval = (const float*)d_in[3];  // [8][512][7200]
    float* out = (float*)d_out;                 // [8][1024][900]

    char* ws = (char*)d_ws;
    // E 103,680,000 | dsum 230,400 | (gap) | mvs 58,982,400 | partials 44,236,800
    // qkT/mkT alias partials (dead before k2_split3b writes partials).
    uint16_t* E        = (uint16_t*)ws;
    float*    dsum     = (float*)(ws + 103680000);
    uint16_t* mvs      = (uint16_t*)(ws + 104140800);
    float*    partials = (float*)(ws + 163123200);
    uint16_t* qkT      = (uint16_t*)(ws + 163123200);
    uint16_t* mkT      = (uint16_t*)(ws + 163123200 + 1843200);

    (void)in_sizes; (void)n_in; (void)out_size; (void)ws_size;

    k_prep<<<dim3(11953), 256, 0, stream>>>(qkey, mkey, qval, out, qkT, mkT, dsum);
    k1_gemm_exp<<<dim3(57, 8, N_), 256, 0, stream>>>(qkT, mkT, E, dsum);
    k_mvs<<<dim3((N_ * CV * M_) / 4 / 256), 256, 0, stream>>>(mval, dsum, mvs);
    k2_split3b<<<dim3(8, 4, N_ * K2_SPLITS), 256, 0, stream>>>(mvs, E, partials);
    k_reduce3<<<dim3((N_ * CV * HW) / 4 / 256), 256, 0, stream>>>(partials, out);
}

// Round 9
// 404.683 us; speedup vs baseline: 1.2099x; 1.0663x over previous
//
#include <hip/hip_runtime.h>
#include <stdint.h>

#define N_  8
#define CK  128
#define CV  512
#define HW  900     // 30*30 queries
#define M_  7200    // 8*30*30 memory slots
#define QK_SCALE 0.08838834764831845f  // 1/sqrt(128)

typedef __attribute__((ext_vector_type(8))) short  short8;
typedef __attribute__((ext_vector_type(4))) float  floatx4;
typedef __attribute__((ext_vector_type(4))) unsigned int   uintx4;
typedef __attribute__((ext_vector_type(4))) unsigned short ushortx4;

__device__ __forceinline__ uint16_t f32_to_bf16(float x) {
    union { float f; uint32_t u; } v; v.f = x;
    return (uint16_t)((v.u + 0x7FFFu + ((v.u >> 16) & 1u)) >> 16);
}

// Direct HBM -> LDS DMA, 16 B per lane. LDS dest is wave-uniform base
// (hardware adds lane*16B); global src is per-lane.
__device__ __forceinline__ void gload_lds16(const uint16_t* g, short* l) {
    __builtin_amdgcn_global_load_lds(
        (const __attribute__((address_space(1))) void*)g,
        (__attribute__((address_space(3))) void*)l,
        16, 0, 0);
}

// counted-vmcnt wait: loads stay in flight across barriers (T4)
#define WAITV(n) asm volatile("s_waitcnt vmcnt(" #n ")" ::: "memory")
// full fence barrier: sched_barrier on BOTH sides so no memory op (incl.
// global_load_lds) migrates across the s_barrier (m152 race class).
#define BARRIER() do { __builtin_amdgcn_sched_barrier(0); \
                       __builtin_amdgcn_s_barrier(); \
                       __builtin_amdgcn_sched_barrier(0); } while (0)

// ---------------------------------------------------------------- fused prep (r8-fixed, passing):
// [0,928)        transpose qkey -> qkT   (29 x 4 x 8 tiles, L=900)
// [928,8128)     transpose mkey -> mkT   (225 x 4 x 8 tiles, L=7200)
// [8128,11728)   copy q_val -> out first half (3600 blocks: N*CV*HW/4/256)
// [11728,11953)  zero dsum (225 blocks)
__device__ __forceinline__ void trans_body(const float* __restrict__ in,
                                           uint16_t* __restrict__ outp, int L,
                                           int bx, int by, int bz, int tid) {
    __shared__ float tile[32][33];
    const int tx = tid & 31;
    const int ty = tid >> 5;
    const int l0 = bx * 32;
    const int c0 = by * 32;
    const float* src = in + (size_t)bz * CK * L;
    uint16_t* dst = outp + (size_t)bz * L * CK;
#pragma unroll
    for (int p = 0; p < 4; p++) {
        int c = c0 + p * 8 + ty;
        int l = l0 + tx;
        float v = 0.f;
        if (l < L) v = src[(size_t)c * L + l];
        tile[p * 8 + ty][tx] = v;
    }
    __syncthreads();
#pragma unroll
    for (int p = 0; p < 4; p++) {
        int l = l0 + p * 8 + ty;
        int c = c0 + tx;
        if (l < L) dst[(size_t)l * CK + c] = f32_to_bf16(tile[tx][p * 8 + ty]);
    }
}

__global__ __launch_bounds__(256) void k_prep(
    const float* __restrict__ qkey, const float* __restrict__ mkey,
    const float* __restrict__ qval, float* __restrict__ out,
    uint16_t* __restrict__ qkT, uint16_t* __restrict__ mkT,
    float* __restrict__ dsum)
{
    const int b = blockIdx.x;
    const int tid = threadIdx.x;
    if (b < 928) {
        trans_body(qkey, qkT, HW, b % 29, (b / 29) & 3, b / 116, tid);
    } else if (b < 8128) {
        const int bb = b - 928;
        trans_body(mkey, mkT, M_, bb % 225, (bb / 225) & 3, bb / 900, tid);
    } else if (b < 11728) {
        const int bb = b - 8128;
        unsigned i = (unsigned)bb * 256 + tid;    // 0..921599
        unsigned e = i * 4u;                      // float index, < 3,686,400
        unsigned n = e / (CV * HW);
        unsigned off = e - n * (CV * HW);
        *(floatx4*)&out[(size_t)n * (2 * CV * HW) + off] = *(const floatx4*)&qval[e];
    } else {
        const int bb = b - 11728;
        int i = bb * 256 + tid;
        if (i < N_ * M_) dsum[i] = 0.f;
    }
}

// ---------------------------------------------------------------- K1: aff = qkT mkT^T, exp, colsum
// Counted-vmcnt 4-buffer pipeline (BK=32, depth 3) — round-4 verbatim (passing).
#define K1_TS 144   // C-tile stride (shorts)

__global__ __launch_bounds__(256) void k1_gemm_exp(
    const uint16_t* __restrict__ qkT,  // [N][HW][CK] bf16 (A: rows q, k=c)
    const uint16_t* __restrict__ mkT,  // [N][M][CK] bf16  (B: rows m, k=c)
    uint16_t* __restrict__ E,          // [N][HW][M] bf16 = exp(aff*scale)
    float* __restrict__ dsum)          // [N][M]
{
    __shared__ __align__(16) short smem[32768];   // 4 bufs x (A 4096 + B 4096)
    __shared__ float colsum[128];

    // XCD swizzle: 3648 blocks, 456/XCD = exactly one n-plane per XCD.
    const int bid = blockIdx.x + 57 * (blockIdx.y + 8 * blockIdx.z);
    const int swz = (bid & 7) * 456 + (bid >> 3);
    const int mb   = swz % 57;
    const int rest = swz / 57;
    const int m0 = mb * 128;
    const int q0 = (rest & 7) * 128;
    const int n  = rest >> 3;
    const int tid = threadIdx.x;

    if (tid < 128) colsum[tid] = 0.f;

    const int lane = tid & 63;
    const int wid  = tid >> 6;
    const int wq   = (wid >> 1) << 6;
    const int wm   = (wid & 1) << 6;
    const int fr   = lane & 15;
    const int quad = lane >> 4;

    const int ca = wid * 2;
    const int rr = lane >> 2;        // row within chunk 0..15
    const int cc = (lane & 3) * 8;   // col (shorts), 16B aligned

    const uint16_t* Ab = qkT + (size_t)n * HW * CK;
    const uint16_t* Bb = mkT + (size_t)n * M_ * CK;
    const uint16_t* A0p = Ab + (size_t)(q0 + ca * 16 + rr) * CK + cc;
    const uint16_t* A1p = A0p + 16 * CK;
    const uint16_t* B0p = Bb + (size_t)(m0 + ca * 16 + rr) * CK + cc;
    const uint16_t* B1p = B0p + 16 * CK;

    floatx4 acc[4][4];
#pragma unroll
    for (int a = 0; a < 4; a++)
#pragma unroll
        for (int b = 0; b < 4; b++) acc[a][b] = (floatx4){0.f, 0.f, 0.f, 0.f};

#define K1_STAGE(buf, ko) do { \
    short* dA = smem + (buf) * 8192 + ca * 512; \
    short* dB = dA + 4096; \
    gload_lds16(A0p + (ko), dA); \
    gload_lds16(A1p + (ko), dA + 512); \
    gload_lds16(B0p + (ko), dB); \
    gload_lds16(B1p + (ko), dB + 512); \
} while (0)

#define K1_COMPUTE(buf) do { \
    const short* bA = smem + (buf) * 8192; \
    const short* bB = bA + 4096; \
    const int k0 = quad * 8; \
    short8 af[4], bfr[4]; \
    _Pragma("unroll") \
    for (int t = 0; t < 4; t++) \
        af[t] = *(const short8*)&bA[(wq + t * 16 + fr) * 32 + k0]; \
    _Pragma("unroll") \
    for (int t = 0; t < 4; t++) \
        bfr[t] = *(const short8*)&bB[(wm + t * 16 + fr) * 32 + k0]; \
    _Pragma("unroll") \
    for (int tq = 0; tq < 4; tq++) \
        _Pragma("unroll") \
        for (int tm = 0; tm < 4; tm++) \
            acc[tq][tm] = __builtin_amdgcn_mfma_f32_16x16x32_bf16( \
                af[tq], bfr[tm], acc[tq][tm], 0, 0, 0); \
} while (0)

    // prefetch depth 3 over 4 K-steps (CK=128, BK=32)
    K1_STAGE(0, 0); K1_STAGE(1, 32); K1_STAGE(2, 64);
    WAITV(8); BARRIER(); K1_STAGE(3, 96); K1_COMPUTE(0);   // t=0
    WAITV(8); BARRIER(); K1_COMPUTE(1);                    // t=1
    WAITV(4); BARRIER(); K1_COMPUTE(2);                    // t=2
    WAITV(0); BARRIER(); K1_COMPUTE(3);                    // t=3

    // ---- epilogue phase A: exp -> LDS C-tile (stride 144), colsum
    __syncthreads();   // all frag reads done; smem reusable as C-tile
    float cs[4] = {0.f, 0.f, 0.f, 0.f};
#pragma unroll
    for (int tq = 0; tq < 4; tq++) {
#pragma unroll
        for (int tm = 0; tm < 4; tm++) {
            const int col = wm + tm * 16 + fr;
#pragma unroll
            for (int i = 0; i < 4; i++) {
                const int row = wq + tq * 16 + quad * 4 + i;
                float e = __expf(acc[tq][tm][i] * QK_SCALE);
                if (q0 + row < HW) cs[tm] += e;   // guard: padded q-rows must not pollute colsum
                smem[row * K1_TS + col] = (short)f32_to_bf16(e);
            }
        }
    }
#pragma unroll
    for (int tm = 0; tm < 4; tm++) {
        float s = cs[tm];
        s += __shfl_xor(s, 16, 64);
        s += __shfl_xor(s, 32, 64);
        if (quad == 0) atomicAdd(&colsum[wm + tm * 16 + fr], s);
    }
    __syncthreads();   // C-tile complete + colsum complete

    // ---- epilogue phase B: coalesced uint4 E-writes (8 per thread)
    uint16_t* En = E + (size_t)n * HW * M_;
#pragma unroll
    for (int j = 0; j < 8; j++) {
        int idx = tid + j * 256;       // 0..2047 = 128 rows x 16 uint4
        int r   = idx >> 4;
        int c8  = (idx & 15) * 8;      // short offset in row
        if (q0 + r < HW && m0 + c8 + 8 <= M_) {
            uintx4 v = *(const uintx4*)&smem[r * K1_TS + c8];
            *(uintx4*)&En[(size_t)(q0 + r) * M_ + m0 + c8] = v;
        }
    }
    if (tid < 128) {
        const int gm = m0 + tid;
        if (gm < M_) atomicAdd(&dsum[(size_t)n * M_ + gm], colsum[tid]);
    }
#undef K1_STAGE
#undef K1_COMPUTE
}

// ---------------------------------------------------------------- mvs = bf16(mv / dsum[m])
__global__ __launch_bounds__(256) void k_mvs(
    const float* __restrict__ mval,   // [N][CV][M]
    const float* __restrict__ dsum,   // [N][M]
    uint16_t* __restrict__ mvs)       // [N][CV][M]
{
    unsigned i = blockIdx.x * 256 + threadIdx.x;
    unsigned base = i * 4u;
    unsigned n = base / (unsigned)(CV * M_);
    unsigned m = base % (unsigned)M_;
    floatx4 v = *(const floatx4*)&mval[base];
    floatx4 d = *(const floatx4*)&dsum[n * (unsigned)M_ + m];
    ushortx4 o;
    o[0] = f32_to_bf16(v[0] * (1.0f / d[0]));
    o[1] = f32_to_bf16(v[1] * (1.0f / d[1]));
    o[2] = f32_to_bf16(v[2] * (1.0f / d[2]));
    o[3] = f32_to_bf16(v[3] * (1.0f / d[3]));
    *(ushortx4*)&mvs[base] = o;
}

// ---------------------------------------------------------------- K2 split x3 — ROUND-4 VERBATIM (139 us, best measured)
// Counted-vmcnt 4-buffer ring (BK=32, prefetch depth 3), BOTH operands
// staged via global_load_lds. Per iter: vmcnt(8) -> barrier -> stage t+3 ->
// MFMA tile t. B-from-global refuted (r5/r6/r8: 170-227 us).
#define K2_SPLITS 3
#define K2_BK 32
#define K2_STEPS 75   // 2400 / 32

__global__ __launch_bounds__(256) void k2_split3(
    const uint16_t* __restrict__ mvs,  // [N][CV][M] bf16 (already / dsum)
    const uint16_t* __restrict__ E,    // [N][HW][M] bf16
    float* __restrict__ partials)      // [3][N][CV][HW]
{
    __shared__ __align__(16) short lds2[32768];   // 4 bufs x (A 4096 + B 4096)

    // XCD swizzle (r4 verbatim): 768 blocks, 96/XCD; q0 fastest -> the 8
    // q-blocks sharing an A-panel are adjacent on one XCD (A L2-resident).
    const int bid = blockIdx.x + 8 * (blockIdx.y + 4 * blockIdx.z);
    const int swz = (bid & 7) * 96 + (bid >> 3);
    const int q0 = (swz & 7) << 7;
    const int c0 = ((swz >> 3) & 3) << 7;
    const int nz = swz >> 5;
    const int n     = nz / K2_SPLITS;
    const int split = nz - n * K2_SPLITS;
    const int tid = threadIdx.x;

    const int lane = tid & 63;
    const int wid  = tid >> 6;
    const int wc   = (wid >> 1) << 6;
    const int wq   = (wid & 1) << 6;
    const int fr   = lane & 15;
    const int quad = lane >> 4;

    // staging geometry: 8 chunks/operand of 1KB (16 rows x 32 cols bf16);
    // wave wid owns chunks {2*wid, 2*wid+1} of A and of B.
    const int ca = wid * 2;
    const int rr = lane >> 2;
    const int cc = (lane & 3) * 8;

    const uint16_t* Asrc = mvs + (size_t)(n * CV + c0) * M_ + split * 2400;
    const uint16_t* Bsrc = E + (size_t)n * HW * M_ + split * 2400;
    const uint16_t* A0p = Asrc + (size_t)(ca * 16 + rr) * M_ + cc;
    const uint16_t* A1p = A0p + (size_t)16 * M_;
    const uint16_t* B0p = Bsrc + (size_t)(q0 + ca * 16 + rr) * M_ + cc;
    const uint16_t* B1p = B0p + (size_t)16 * M_;

    floatx4 acc[4][4];
#pragma unroll
    for (int a = 0; a < 4; a++)
#pragma unroll
        for (int b = 0; b < 4; b++) acc[a][b] = (floatx4){0.f, 0.f, 0.f, 0.f};

#define K2_STAGE(buf, mo) do { \
    short* dA = lds2 + (buf) * 8192 + ca * 512; \
    short* dB = dA + 4096; \
    gload_lds16(A0p + (mo), dA); \
    gload_lds16(A1p + (mo), dA + 512); \
    gload_lds16(B0p + (mo), dB); \
    gload_lds16(B1p + (mo), dB + 512); \
} while (0)

#define K2_COMPUTE(buf) do { \
    const short* bA = lds2 + (buf) * 8192; \
    const short* bB = bA + 4096; \
    const int k0 = quad * 8; \
    short8 af[4], bfr[4]; \
    _Pragma("unroll") \
    for (int t = 0; t < 4; t++) \
        af[t] = *(const short8*)&bA[(wc + t * 16 + fr) * 32 + k0]; \
    _Pragma("unroll") \
    for (int t = 0; t < 4; t++) \
        bfr[t] = *(const short8*)&bB[(wq + t * 16 + fr) * 32 + k0]; \
    _Pragma("unroll") \
    for (int tc = 0; tc < 4; tc++) \
        _Pragma("unroll") \
        for (int tq = 0; tq < 4; tq++) \
            acc[tc][tq] = __builtin_amdgcn_mfma_f32_16x16x32_bf16( \
                af[tc], bfr[tq], acc[tc][tq], 0, 0, 0); \
} while (0)

    K2_STAGE(0, 0);
    K2_STAGE(1, K2_BK);
    K2_STAGE(2, 2 * K2_BK);
    for (int t = 0; t < K2_STEPS - 3; ++t) {      // t = 0..71
        WAITV(8); BARRIER();
        K2_STAGE((t + 3) & 3, (t + 3) * K2_BK);
        K2_COMPUTE(t & 3);
    }
    WAITV(8); BARRIER(); K2_COMPUTE(0);           // t=72 (72&3==0)
    WAITV(4); BARRIER(); K2_COMPUTE(1);           // t=73
    WAITV(0); BARRIER(); K2_COMPUTE(2);           // t=74

    float* P = partials + ((size_t)split * N_ + n) * CV * HW;
#pragma unroll
    for (int tc = 0; tc < 4; tc++) {
#pragma unroll
        for (int tq = 0; tq < 4; tq++) {
            const int gq = q0 + wq + tq * 16 + fr;
            if (gq < HW) {
#pragma unroll
                for (int i = 0; i < 4; i++) {
                    const int gc = c0 + wc + tc * 16 + quad * 4 + i;
                    P[(size_t)gc * HW + gq] = acc[tc][tq][i];
                }
            }
        }
    }
#undef K2_STAGE
#undef K2_COMPUTE
}

// ---------------------------------------------------------------- reduce 3 partials -> out mapped half
__global__ __launch_bounds__(256) void k_reduce3(const float* __restrict__ partials,
                                                 float* __restrict__ out) {
    unsigned i = blockIdx.x * 256 + threadIdx.x;
    unsigned e = i * 4u;
    unsigned n = e / (CV * HW);
    unsigned off = e - n * (CV * HW);
    const size_t stride = (size_t)N_ * CV * HW;
    const float* p = partials + (size_t)n * CV * HW + off;
    floatx4 a = *(const floatx4*)&p[0];
    floatx4 b = *(const floatx4*)&p[stride];
    floatx4 c = *(const floatx4*)&p[2 * stride];
    floatx4 s = a + b + c;
    *(floatx4*)&out[(size_t)n * (2 * CV * HW) + CV * HW + off] = s;
}

// ----------------------------------------------------------------
extern "C" void kernel_launch(void* const* d_in, const int* in_sizes, int n_in,
                              void* d_out, int out_size, void* d_ws, size_t ws_size,
                              hipStream_t stream) {
    const float* qkey = (const float*)d_in[0];  // [8][128][900]
    const float* qval = (const float*)d_in[1];  // [8][512][900]
    const float* mkey = (const float*)d_in[2];  // [8][128][7200]
    const float* mval = (const float*)d_in[3];  // [8][512][7200]
    float* out = (float*)d_out;                 // [8][1024][900]

    char* ws = (char*)d_ws;
    // E 103,680,000 | dsum 230,400 | (gap) | mvs 58,982,400 | partials 44,236,800
    // qkT/mkT alias partials (dead before k2_split3 writes partials).
    uint16_t* E        = (uint16_t*)ws;
    float*    dsum     = (float*)(ws + 103680000);
    uint16_t* mvs      = (uint16_t*)(ws + 104140800);
    float*    partials = (float*)(ws + 163123200);
    uint16_t* qkT      = (uint16_t*)(ws + 163123200);
    uint16_t* mkT      = (uint16_t*)(ws + 163123200 + 1843200);

    (void)in_sizes; (void)n_in; (void)out_size; (void)ws_size;

    k_prep<<<dim3(11953), 256, 0, stream>>>(qkey, mkey, qval, out, qkT, mkT, dsum);
    k1_gemm_exp<<<dim3(57, 8, N_), 256, 0, stream>>>(qkT, mkT, E, dsum);
    k_mvs<<<dim3((N_ * CV * M_) / 4 / 256), 256, 0, stream>>>(mval, dsum, mvs);
    k2_split3<<<dim3(8, 4, N_ * K2_SPLITS), 256, 0, stream>>>(mvs, E, partials);
    k_reduce3<<<dim3((N_ * CV * HW) / 4 / 256), 256, 0, stream>>>(partials, out);
}

// Round 10
// 402.798 us; speedup vs baseline: 1.2155x; 1.0047x over previous
//
#include <hip/hip_runtime.h>
#include <stdint.h>

#define N_  8
#define CK  128
#define CV  512
#define HW  900     // 30*30 queries
#define M_  7200    // 8*30*30 memory slots
#define QK_SCALE 0.08838834764831845f  // 1/sqrt(128)

typedef __attribute__((ext_vector_type(8))) short  short8;
typedef __attribute__((ext_vector_type(4))) float  floatx4;
typedef __attribute__((ext_vector_type(4))) unsigned int   uintx4;
typedef __attribute__((ext_vector_type(4))) unsigned short ushortx4;

__device__ __forceinline__ uint16_t f32_to_bf16(float x) {
    union { float f; uint32_t u; } v; v.f = x;
    return (uint16_t)((v.u + 0x7FFFu + ((v.u >> 16) & 1u)) >> 16);
}

// Direct HBM -> LDS DMA, 16 B per lane. LDS dest is wave-uniform base
// (hardware adds lane*16B); global src is per-lane.
__device__ __forceinline__ void gload_lds16(const uint16_t* g, short* l) {
    __builtin_amdgcn_global_load_lds(
        (const __attribute__((address_space(1))) void*)g,
        (__attribute__((address_space(3))) void*)l,
        16, 0, 0);
}

// counted-vmcnt wait: loads stay in flight across barriers (T4)
#define WAITV(n) asm volatile("s_waitcnt vmcnt(" #n ")" ::: "memory")
// full fence barrier: sched_barrier on BOTH sides so no memory op (incl.
// global_load_lds) migrates across the s_barrier (m152 race class).
#define BARRIER() do { __builtin_amdgcn_sched_barrier(0); \
                       __builtin_amdgcn_s_barrier(); \
                       __builtin_amdgcn_sched_barrier(0); } while (0)

// ---------------------------------------------------------------- fused prep (r8-fixed, passing):
// [0,928)        transpose qkey -> qkT   (29 x 4 x 8 tiles, L=900)
// [928,8128)     transpose mkey -> mkT   (225 x 4 x 8 tiles, L=7200)
// [8128,11728)   copy q_val -> out first half (3600 blocks: N*CV*HW/4/256)
// [11728,11953)  zero dsum (225 blocks)
__device__ __forceinline__ void trans_body(const float* __restrict__ in,
                                           uint16_t* __restrict__ outp, int L,
                                           int bx, int by, int bz, int tid) {
    __shared__ float tile[32][33];
    const int tx = tid & 31;
    const int ty = tid >> 5;
    const int l0 = bx * 32;
    const int c0 = by * 32;
    const float* src = in + (size_t)bz * CK * L;
    uint16_t* dst = outp + (size_t)bz * L * CK;
#pragma unroll
    for (int p = 0; p < 4; p++) {
        int c = c0 + p * 8 + ty;
        int l = l0 + tx;
        float v = 0.f;
        if (l < L) v = src[(size_t)c * L + l];
        tile[p * 8 + ty][tx] = v;
    }
    __syncthreads();
#pragma unroll
    for (int p = 0; p < 4; p++) {
        int l = l0 + p * 8 + ty;
        int c = c0 + tx;
        if (l < L) dst[(size_t)l * CK + c] = f32_to_bf16(tile[tx][p * 8 + ty]);
    }
}

__global__ __launch_bounds__(256) void k_prep(
    const float* __restrict__ qkey, const float* __restrict__ mkey,
    const float* __restrict__ qval, float* __restrict__ out,
    uint16_t* __restrict__ qkT, uint16_t* __restrict__ mkT,
    float* __restrict__ dsum)
{
    const int b = blockIdx.x;
    const int tid = threadIdx.x;
    if (b < 928) {
        trans_body(qkey, qkT, HW, b % 29, (b / 29) & 3, b / 116, tid);
    } else if (b < 8128) {
        const int bb = b - 928;
        trans_body(mkey, mkT, M_, bb % 225, (bb / 225) & 3, bb / 900, tid);
    } else if (b < 11728) {
        const int bb = b - 8128;
        unsigned i = (unsigned)bb * 256 + tid;    // 0..921599
        unsigned e = i * 4u;                      // float index, < 3,686,400
        unsigned n = e / (CV * HW);
        unsigned off = e - n * (CV * HW);
        *(floatx4*)&out[(size_t)n * (2 * CV * HW) + off] = *(const floatx4*)&qval[e];
    } else {
        const int bb = b - 11728;
        int i = bb * 256 + tid;
        if (i < N_ * M_) dsum[i] = 0.f;
    }
}

// ---------------------------------------------------------------- K1: aff = qkT mkT^T, exp, colsum
// Ring-3 depth-2 counted-vmcnt pipeline (BK=32): 48 KB staging -> 3 blocks/CU
// (was 64 KB / 2 blocks). Depth-2 cover ~2 step-times > HBM latency.
// Ledger (4 loads/wave/stage): prologue 2 stages = 8 out; WAITV(4) drains
// tile t; stage t+2 -> buf (t+2)%3 (last read t-1, behind barrier: WAR-safe).
#define K1_TS 144   // C-tile stride (shorts)

__global__ __launch_bounds__(256) void k1_gemm_exp(
    const uint16_t* __restrict__ qkT,  // [N][HW][CK] bf16 (A: rows q, k=c)
    const uint16_t* __restrict__ mkT,  // [N][M][CK] bf16  (B: rows m, k=c)
    uint16_t* __restrict__ E,          // [N][HW][M] bf16 = exp(aff*scale)
    float* __restrict__ dsum)          // [N][M]
{
    __shared__ __align__(16) short smem[24576];   // 3 bufs x (A 4096 + B 4096); C-tile 18432 fits
    __shared__ float colsum[128];

    // XCD swizzle: 3648 blocks, 456/XCD = exactly one n-plane per XCD.
    const int bid = blockIdx.x + 57 * (blockIdx.y + 8 * blockIdx.z);
    const int swz = (bid & 7) * 456 + (bid >> 3);
    const int mb   = swz % 57;
    const int rest = swz / 57;
    const int m0 = mb * 128;
    const int q0 = (rest & 7) * 128;
    const int n  = rest >> 3;
    const int tid = threadIdx.x;

    if (tid < 128) colsum[tid] = 0.f;

    const int lane = tid & 63;
    const int wid  = tid >> 6;
    const int wq   = (wid >> 1) << 6;
    const int wm   = (wid & 1) << 6;
    const int fr   = lane & 15;
    const int quad = lane >> 4;

    const int ca = wid * 2;
    const int rr = lane >> 2;        // row within chunk 0..15
    const int cc = (lane & 3) * 8;   // col (shorts), 16B aligned

    const uint16_t* Ab = qkT + (size_t)n * HW * CK;
    const uint16_t* Bb = mkT + (size_t)n * M_ * CK;
    const uint16_t* A0p = Ab + (size_t)(q0 + ca * 16 + rr) * CK + cc;
    const uint16_t* A1p = A0p + 16 * CK;
    const uint16_t* B0p = Bb + (size_t)(m0 + ca * 16 + rr) * CK + cc;
    const uint16_t* B1p = B0p + 16 * CK;

    floatx4 acc[4][4];
#pragma unroll
    for (int a = 0; a < 4; a++)
#pragma unroll
        for (int b = 0; b < 4; b++) acc[a][b] = (floatx4){0.f, 0.f, 0.f, 0.f};

#define K1_STAGE(buf, ko) do { \
    short* dA = smem + (buf) * 8192 + ca * 512; \
    short* dB = dA + 4096; \
    gload_lds16(A0p + (ko), dA); \
    gload_lds16(A1p + (ko), dA + 512); \
    gload_lds16(B0p + (ko), dB); \
    gload_lds16(B1p + (ko), dB + 512); \
} while (0)

#define K1_COMPUTE(buf) do { \
    const short* bA = smem + (buf) * 8192; \
    const short* bB = bA + 4096; \
    const int k0 = quad * 8; \
    short8 af[4], bfr[4]; \
    _Pragma("unroll") \
    for (int t = 0; t < 4; t++) \
        af[t] = *(const short8*)&bA[(wq + t * 16 + fr) * 32 + k0]; \
    _Pragma("unroll") \
    for (int t = 0; t < 4; t++) \
        bfr[t] = *(const short8*)&bB[(wm + t * 16 + fr) * 32 + k0]; \
    _Pragma("unroll") \
    for (int tq = 0; tq < 4; tq++) \
        _Pragma("unroll") \
        for (int tm = 0; tm < 4; tm++) \
            acc[tq][tm] = __builtin_amdgcn_mfma_f32_16x16x32_bf16( \
                af[tq], bfr[tm], acc[tq][tm], 0, 0, 0); \
} while (0)

    // ring-3 depth-2 over 4 K-steps (tiles 0..3; tile->buf = tile%3)
    K1_STAGE(0, 0); K1_STAGE(1, 32);
    WAITV(4); BARRIER(); K1_STAGE(2, 64); K1_COMPUTE(0);   // t=0
    WAITV(4); BARRIER(); K1_STAGE(0, 96); K1_COMPUTE(1);   // t=1 (tile3->buf0)
    WAITV(4); BARRIER(); K1_COMPUTE(2);                    // t=2
    WAITV(0); BARRIER(); K1_COMPUTE(0);                    // t=3 (tile3 in buf0)

    // ---- epilogue phase A: exp -> LDS C-tile (stride 144), colsum
    __syncthreads();   // all frag reads done; smem reusable as C-tile
    float cs[4] = {0.f, 0.f, 0.f, 0.f};
#pragma unroll
    for (int tq = 0; tq < 4; tq++) {
#pragma unroll
        for (int tm = 0; tm < 4; tm++) {
            const int col = wm + tm * 16 + fr;
#pragma unroll
            for (int i = 0; i < 4; i++) {
                const int row = wq + tq * 16 + quad * 4 + i;
                float e = __expf(acc[tq][tm][i] * QK_SCALE);
                if (q0 + row < HW) cs[tm] += e;   // guard: padded q-rows must not pollute colsum
                smem[row * K1_TS + col] = (short)f32_to_bf16(e);
            }
        }
    }
#pragma unroll
    for (int tm = 0; tm < 4; tm++) {
        float s = cs[tm];
        s += __shfl_xor(s, 16, 64);
        s += __shfl_xor(s, 32, 64);
        if (quad == 0) atomicAdd(&colsum[wm + tm * 16 + fr], s);
    }
    __syncthreads();   // C-tile complete + colsum complete

    // ---- epilogue phase B: coalesced uint4 E-writes (8 per thread)
    uint16_t* En = E + (size_t)n * HW * M_;
#pragma unroll
    for (int j = 0; j < 8; j++) {
        int idx = tid + j * 256;       // 0..2047 = 128 rows x 16 uint4
        int r   = idx >> 4;
        int c8  = (idx & 15) * 8;      // short offset in row
        if (q0 + r < HW && m0 + c8 + 8 <= M_) {
            uintx4 v = *(const uintx4*)&smem[r * K1_TS + c8];
            *(uintx4*)&En[(size_t)(q0 + r) * M_ + m0 + c8] = v;
        }
    }
    if (tid < 128) {
        const int gm = m0 + tid;
        if (gm < M_) atomicAdd(&dsum[(size_t)n * M_ + gm], colsum[tid]);
    }
#undef K1_STAGE
#undef K1_COMPUTE
}

// ---------------------------------------------------------------- mvs = bf16(mv / dsum[m])
__global__ __launch_bounds__(256) void k_mvs(
    const float* __restrict__ mval,   // [N][CV][M]
    const float* __restrict__ dsum,   // [N][M]
    uint16_t* __restrict__ mvs)       // [N][CV][M]
{
    unsigned i = blockIdx.x * 256 + threadIdx.x;
    unsigned base = i * 4u;
    unsigned n = base / (unsigned)(CV * M_);
    unsigned m = base % (unsigned)M_;
    floatx4 v = *(const floatx4*)&mval[base];
    floatx4 d = *(const floatx4*)&dsum[n * (unsigned)M_ + m];
    ushortx4 o;
    o[0] = f32_to_bf16(v[0] * (1.0f / d[0]));
    o[1] = f32_to_bf16(v[1] * (1.0f / d[1]));
    o[2] = f32_to_bf16(v[2] * (1.0f / d[2]));
    o[3] = f32_to_bf16(v[3] * (1.0f / d[3]));
    *(ushortx4*)&mvs[base] = o;
}

// ---------------------------------------------------------------- K2 split x3 — ring-3 depth-2
// r4's verified schedule with the ring cut 4->3 bufs: 48 KB LDS -> 3 blocks/CU
// co-resident (768-block grid = exactly 3/CU, perfect balance). Cross-block
// overlap attacks the ~2x bubble over the LDS-traffic floor seen at 2/CU.
// Ledger (4 loads/wave/stage): prologue 2 stages = 8 out; WAITV(4) drains
// tile t; stage t+2 -> buf (t+2)%3 (last read at t-1, behind barrier).
#define K2_SPLITS 3
#define K2_BK 32
#define K2_STEPS 75   // 2400 / 32

__global__ __launch_bounds__(256) void k2_split3(
    const uint16_t* __restrict__ mvs,  // [N][CV][M] bf16 (already / dsum)
    const uint16_t* __restrict__ E,    // [N][HW][M] bf16
    float* __restrict__ partials)      // [3][N][CV][HW]
{
    __shared__ __align__(16) short lds2[24576];   // 3 bufs x (A 4096 + B 4096)

    // XCD swizzle (r4 verbatim): 768 blocks, 96/XCD; q0 fastest -> the 8
    // q-blocks sharing an A-panel are adjacent on one XCD (A L2-resident).
    const int bid = blockIdx.x + 8 * (blockIdx.y + 4 * blockIdx.z);
    const int swz = (bid & 7) * 96 + (bid >> 3);
    const int q0 = (swz & 7) << 7;
    const int c0 = ((swz >> 3) & 3) << 7;
    const int nz = swz >> 5;
    const int n     = nz / K2_SPLITS;
    const int split = nz - n * K2_SPLITS;
    const int tid = threadIdx.x;

    const int lane = tid & 63;
    const int wid  = tid >> 6;
    const int wc   = (wid >> 1) << 6;
    const int wq   = (wid & 1) << 6;
    const int fr   = lane & 15;
    const int quad = lane >> 4;

    // staging geometry: 8 chunks/operand of 1KB (16 rows x 32 cols bf16);
    // wave wid owns chunks {2*wid, 2*wid+1} of A and of B.
    const int ca = wid * 2;
    const int rr = lane >> 2;
    const int cc = (lane & 3) * 8;

    const uint16_t* Asrc = mvs + (size_t)(n * CV + c0) * M_ + split * 2400;
    const uint16_t* Bsrc = E + (size_t)n * HW * M_ + split * 2400;
    const uint16_t* A0p = Asrc + (size_t)(ca * 16 + rr) * M_ + cc;
    const uint16_t* A1p = A0p + (size_t)16 * M_;
    const uint16_t* B0p = Bsrc + (size_t)(q0 + ca * 16 + rr) * M_ + cc;
    const uint16_t* B1p = B0p + (size_t)16 * M_;

    floatx4 acc[4][4];
#pragma unroll
    for (int a = 0; a < 4; a++)
#pragma unroll
        for (int b = 0; b < 4; b++) acc[a][b] = (floatx4){0.f, 0.f, 0.f, 0.f};

#define K2_STAGE(buf, mo) do { \
    short* dA = lds2 + (buf) * 8192 + ca * 512; \
    short* dB = dA + 4096; \
    gload_lds16(A0p + (mo), dA); \
    gload_lds16(A1p + (mo), dA + 512); \
    gload_lds16(B0p + (mo), dB); \
    gload_lds16(B1p + (mo), dB + 512); \
} while (0)

#define K2_COMPUTE(buf) do { \
    const short* bA = lds2 + (buf) * 8192; \
    const short* bB = bA + 4096; \
    const int k0 = quad * 8; \
    short8 af[4], bfr[4]; \
    _Pragma("unroll") \
    for (int t = 0; t < 4; t++) \
        af[t] = *(const short8*)&bA[(wc + t * 16 + fr) * 32 + k0]; \
    _Pragma("unroll") \
    for (int t = 0; t < 4; t++) \
        bfr[t] = *(const short8*)&bB[(wq + t * 16 + fr) * 32 + k0]; \
    _Pragma("unroll") \
    for (int tc = 0; tc < 4; tc++) \
        _Pragma("unroll") \
        for (int tq = 0; tq < 4; tq++) \
            acc[tc][tq] = __builtin_amdgcn_mfma_f32_16x16x32_bf16( \
                af[tc], bfr[tq], acc[tc][tq], 0, 0, 0); \
} while (0)

    // ring-3 depth-2 over 75 tiles (tile->buf = tile%3)
    K2_STAGE(0, 0);
    K2_STAGE(1, K2_BK);
    for (int s = 0; s < 24; s++) {                // t = 3s..3s+2 (0..71)
        int mo = (3 * s + 2) * K2_BK;
        WAITV(4); BARRIER();
        K2_STAGE(2, mo); K2_COMPUTE(0);           // t=3s:   stage tile t+2 -> buf2
        WAITV(4); BARRIER();
        K2_STAGE(0, mo + K2_BK); K2_COMPUTE(1);   // t=3s+1: -> buf0
        WAITV(4); BARRIER();
        K2_STAGE(1, mo + 2 * K2_BK); K2_COMPUTE(2); // t=3s+2: -> buf1
    }
    // t=72: stage tile 74 -> buf2; compute tile 72 (buf0)
    WAITV(4); BARRIER();
    K2_STAGE(2, 74 * K2_BK); K2_COMPUTE(0);
    // t=73: compute tile 73 (buf1)
    WAITV(4); BARRIER();
    K2_COMPUTE(1);
    // t=74: compute tile 74 (buf2)
    WAITV(0); BARRIER();
    K2_COMPUTE(2);

    float* P = partials + ((size_t)split * N_ + n) * CV * HW;
#pragma unroll
    for (int tc = 0; tc < 4; tc++) {
#pragma unroll
        for (int tq = 0; tq < 4; tq++) {
            const int gq = q0 + wq + tq * 16 + fr;
            if (gq < HW) {
#pragma unroll
                for (int i = 0; i < 4; i++) {
                    const int gc = c0 + wc + tc * 16 + quad * 4 + i;
                    P[(size_t)gc * HW + gq] = acc[tc][tq][i];
                }
            }
        }
    }
#undef K2_STAGE
#undef K2_COMPUTE
}

// ---------------------------------------------------------------- reduce 3 partials -> out mapped half
__global__ __launch_bounds__(256) void k_reduce3(const float* __restrict__ partials,
                                                 float* __restrict__ out) {
    unsigned i = blockIdx.x * 256 + threadIdx.x;
    unsigned e = i * 4u;
    unsigned n = e / (CV * HW);
    unsigned off = e - n * (CV * HW);
    const size_t stride = (size_t)N_ * CV * HW;
    const float* p = partials + (size_t)n * CV * HW + off;
    floatx4 a = *(const floatx4*)&p[0];
    floatx4 b = *(const floatx4*)&p[stride];
    floatx4 c = *(const floatx4*)&p[2 * stride];
    floatx4 s = a + b + c;
    *(floatx4*)&out[(size_t)n * (2 * CV * HW) + CV * HW + off] = s;
}

// ----------------------------------------------------------------
extern "C" void kernel_launch(void* const* d_in, const int* in_sizes, int n_in,
                              void* d_out, int out_size, void* d_ws, size_t ws_size,
                              hipStream_t stream) {
    const float* qkey = (const float*)d_in[0];  // [8][128][900]
    const float* qval = (const float*)d_in[1];  // [8][512][900]
    const float* mkey = (const float*)d_in[2];  // [8][128][7200]
    const float* mval = (const float*)d_in[3];  // [8][512][7200]
    float* out = (float*)d_out;                 // [8][1024][900]

    char* ws = (char*)d_ws;
    // E 103,680,000 | dsum 230,400 | (gap) | mvs 58,982,400 | partials 44,236,800
    // qkT/mkT alias partials (dead before k2_split3 writes partials).
    uint16_t* E        = (uint16_t*)ws;
    float*    dsum     = (float*)(ws + 103680000);
    uint16_t* mvs      = (uint16_t*)(ws + 104140800);
    float*    partials = (float*)(ws + 163123200);
    uint16_t* qkT      = (uint16_t*)(ws + 163123200);
    uint16_t* mkT      = (uint16_t*)(ws + 163123200 + 1843200);

    (void)in_sizes; (void)n_in; (void)out_size; (void)ws_size;

    k_prep<<<dim3(11953), 256, 0, stream>>>(qkey, mkey, qval, out, qkT, mkT, dsum);
    k1_gemm_exp<<<dim3(57, 8, N_), 256, 0, stream>>>(qkT, mkT, E, dsum);
    k_mvs<<<dim3((N_ * CV * M_) / 4 / 256), 256, 0, stream>>>(mval, dsum, mvs);
    k2_split3<<<dim3(8, 4, N_ * K2_SPLITS), 256, 0, stream>>>(mvs, E, partials);
    k_reduce3<<<dim3((N_ * CV * HW) / 4 / 256), 256, 0, stream>>>(partials, out);
}

// Round 11
// 388.287 us; speedup vs baseline: 1.2610x; 1.0374x over previous
//
#include <hip/hip_runtime.h>
#include <stdint.h>

#define N_  8
#define CK  128
#define CV  512
#define HW  900     // 30*30 queries
#define M_  7200    // 8*30*30 memory slots
#define QK_SCALE 0.08838834764831845f  // 1/sqrt(128)

typedef __attribute__((ext_vector_type(8))) short  short8;
typedef __attribute__((ext_vector_type(4))) float  floatx4;
typedef __attribute__((ext_vector_type(4))) unsigned int   uintx4;
typedef __attribute__((ext_vector_type(4))) unsigned short ushortx4;

__device__ __forceinline__ uint16_t f32_to_bf16(float x) {
    union { float f; uint32_t u; } v; v.f = x;
    return (uint16_t)((v.u + 0x7FFFu + ((v.u >> 16) & 1u)) >> 16);
}

// Direct HBM -> LDS DMA, 16 B per lane. LDS dest is wave-uniform base
// (hardware adds lane*16B); global src is per-lane.
__device__ __forceinline__ void gload_lds16(const uint16_t* g, short* l) {
    __builtin_amdgcn_global_load_lds(
        (const __attribute__((address_space(1))) void*)g,
        (__attribute__((address_space(3))) void*)l,
        16, 0, 0);
}

// counted-vmcnt wait: loads stay in flight across barriers (T4)
#define WAITV(n) asm volatile("s_waitcnt vmcnt(" #n ")" ::: "memory")
// full fence barrier: sched_barrier on BOTH sides so no memory op (incl.
// global_load_lds) migrates across the s_barrier (m152 race class).
#define BARRIER() do { __builtin_amdgcn_sched_barrier(0); \
                       __builtin_amdgcn_s_barrier(); \
                       __builtin_amdgcn_sched_barrier(0); } while (0)

// ---------------------------------------------------------------- fused prep (r8-fixed, passing):
// [0,928)        transpose qkey -> qkT   (29 x 4 x 8 tiles, L=900)
// [928,8128)     transpose mkey -> mkT   (225 x 4 x 8 tiles, L=7200)
// [8128,11728)   copy q_val -> out first half (3600 blocks: N*CV*HW/4/256)
// [11728,11953)  zero dsum (225 blocks)
__device__ __forceinline__ void trans_body(const float* __restrict__ in,
                                           uint16_t* __restrict__ outp, int L,
                                           int bx, int by, int bz, int tid) {
    __shared__ float tile[32][33];
    const int tx = tid & 31;
    const int ty = tid >> 5;
    const int l0 = bx * 32;
    const int c0 = by * 32;
    const float* src = in + (size_t)bz * CK * L;
    uint16_t* dst = outp + (size_t)bz * L * CK;
#pragma unroll
    for (int p = 0; p < 4; p++) {
        int c = c0 + p * 8 + ty;
        int l = l0 + tx;
        float v = 0.f;
        if (l < L) v = src[(size_t)c * L + l];
        tile[p * 8 + ty][tx] = v;
    }
    __syncthreads();
#pragma unroll
    for (int p = 0; p < 4; p++) {
        int l = l0 + p * 8 + ty;
        int c = c0 + tx;
        if (l < L) dst[(size_t)l * CK + c] = f32_to_bf16(tile[tx][p * 8 + ty]);
    }
}

__global__ __launch_bounds__(256) void k_prep(
    const float* __restrict__ qkey, const float* __restrict__ mkey,
    const float* __restrict__ qval, float* __restrict__ out,
    uint16_t* __restrict__ qkT, uint16_t* __restrict__ mkT,
    float* __restrict__ dsum)
{
    const int b = blockIdx.x;
    const int tid = threadIdx.x;
    if (b < 928) {
        trans_body(qkey, qkT, HW, b % 29, (b / 29) & 3, b / 116, tid);
    } else if (b < 8128) {
        const int bb = b - 928;
        trans_body(mkey, mkT, M_, bb % 225, (bb / 225) & 3, bb / 900, tid);
    } else if (b < 11728) {
        const int bb = b - 8128;
        unsigned i = (unsigned)bb * 256 + tid;    // 0..921599
        unsigned e = i * 4u;                      // float index, < 3,686,400
        unsigned n = e / (CV * HW);
        unsigned off = e - n * (CV * HW);
        *(floatx4*)&out[(size_t)n * (2 * CV * HW) + off] = *(const floatx4*)&qval[e];
    } else {
        const int bb = b - 11728;
        int i = bb * 256 + tid;
        if (i < N_ * M_) dsum[i] = 0.f;
    }
}

// ---------------------------------------------------------------- K1: aff = qkT mkT^T, exp, colsum
// Ring-3 depth-2 counted-vmcnt pipeline (BK=32) — r10 verbatim (passing).
#define K1_TS 144   // C-tile stride (shorts)

__global__ __launch_bounds__(256) void k1_gemm_exp(
    const uint16_t* __restrict__ qkT,  // [N][HW][CK] bf16 (A: rows q, k=c)
    const uint16_t* __restrict__ mkT,  // [N][M][CK] bf16  (B: rows m, k=c)
    uint16_t* __restrict__ E,          // [N][HW][M] bf16 = exp(aff*scale)
    float* __restrict__ dsum)          // [N][M]
{
    __shared__ __align__(16) short smem[24576];   // 3 bufs x (A 4096 + B 4096); C-tile 18432 fits
    __shared__ float colsum[128];

    // XCD swizzle: 3648 blocks, 456/XCD = exactly one n-plane per XCD.
    const int bid = blockIdx.x + 57 * (blockIdx.y + 8 * blockIdx.z);
    const int swz = (bid & 7) * 456 + (bid >> 3);
    const int mb   = swz % 57;
    const int rest = swz / 57;
    const int m0 = mb * 128;
    const int q0 = (rest & 7) * 128;
    const int n  = rest >> 3;
    const int tid = threadIdx.x;

    if (tid < 128) colsum[tid] = 0.f;

    const int lane = tid & 63;
    const int wid  = tid >> 6;
    const int wq   = (wid >> 1) << 6;
    const int wm   = (wid & 1) << 6;
    const int fr   = lane & 15;
    const int quad = lane >> 4;

    const int ca = wid * 2;
    const int rr = lane >> 2;        // row within chunk 0..15
    const int cc = (lane & 3) * 8;   // col (shorts), 16B aligned

    const uint16_t* Ab = qkT + (size_t)n * HW * CK;
    const uint16_t* Bb = mkT + (size_t)n * M_ * CK;
    const uint16_t* A0p = Ab + (size_t)(q0 + ca * 16 + rr) * CK + cc;
    const uint16_t* A1p = A0p + 16 * CK;
    const uint16_t* B0p = Bb + (size_t)(m0 + ca * 16 + rr) * CK + cc;
    const uint16_t* B1p = B0p + 16 * CK;

    floatx4 acc[4][4];
#pragma unroll
    for (int a = 0; a < 4; a++)
#pragma unroll
        for (int b = 0; b < 4; b++) acc[a][b] = (floatx4){0.f, 0.f, 0.f, 0.f};

#define K1_STAGE(buf, ko) do { \
    short* dA = smem + (buf) * 8192 + ca * 512; \
    short* dB = dA + 4096; \
    gload_lds16(A0p + (ko), dA); \
    gload_lds16(A1p + (ko), dA + 512); \
    gload_lds16(B0p + (ko), dB); \
    gload_lds16(B1p + (ko), dB + 512); \
} while (0)

#define K1_COMPUTE(buf) do { \
    const short* bA = smem + (buf) * 8192; \
    const short* bB = bA + 4096; \
    const int k0 = quad * 8; \
    short8 af[4], bfr[4]; \
    _Pragma("unroll") \
    for (int t = 0; t < 4; t++) \
        af[t] = *(const short8*)&bA[(wq + t * 16 + fr) * 32 + k0]; \
    _Pragma("unroll") \
    for (int t = 0; t < 4; t++) \
        bfr[t] = *(const short8*)&bB[(wm + t * 16 + fr) * 32 + k0]; \
    _Pragma("unroll") \
    for (int tq = 0; tq < 4; tq++) \
        _Pragma("unroll") \
        for (int tm = 0; tm < 4; tm++) \
            acc[tq][tm] = __builtin_amdgcn_mfma_f32_16x16x32_bf16( \
                af[tq], bfr[tm], acc[tq][tm], 0, 0, 0); \
} while (0)

    // ring-3 depth-2 over 4 K-steps (tiles 0..3; tile->buf = tile%3)
    K1_STAGE(0, 0); K1_STAGE(1, 32);
    WAITV(4); BARRIER(); K1_STAGE(2, 64); K1_COMPUTE(0);   // t=0
    WAITV(4); BARRIER(); K1_STAGE(0, 96); K1_COMPUTE(1);   // t=1 (tile3->buf0)
    WAITV(4); BARRIER(); K1_COMPUTE(2);                    // t=2
    WAITV(0); BARRIER(); K1_COMPUTE(0);                    // t=3 (tile3 in buf0)

    // ---- epilogue phase A: exp -> LDS C-tile (stride 144), colsum
    __syncthreads();   // all frag reads done; smem reusable as C-tile
    float cs[4] = {0.f, 0.f, 0.f, 0.f};
#pragma unroll
    for (int tq = 0; tq < 4; tq++) {
#pragma unroll
        for (int tm = 0; tm < 4; tm++) {
            const int col = wm + tm * 16 + fr;
#pragma unroll
            for (int i = 0; i < 4; i++) {
                const int row = wq + tq * 16 + quad * 4 + i;
                float e = __expf(acc[tq][tm][i] * QK_SCALE);
                if (q0 + row < HW) cs[tm] += e;   // guard: padded q-rows must not pollute colsum
                smem[row * K1_TS + col] = (short)f32_to_bf16(e);
            }
        }
    }
#pragma unroll
    for (int tm = 0; tm < 4; tm++) {
        float s = cs[tm];
        s += __shfl_xor(s, 16, 64);
        s += __shfl_xor(s, 32, 64);
        if (quad == 0) atomicAdd(&colsum[wm + tm * 16 + fr], s);
    }
    __syncthreads();   // C-tile complete + colsum complete

    // ---- epilogue phase B: coalesced uint4 E-writes (8 per thread)
    uint16_t* En = E + (size_t)n * HW * M_;
#pragma unroll
    for (int j = 0; j < 8; j++) {
        int idx = tid + j * 256;       // 0..2047 = 128 rows x 16 uint4
        int r   = idx >> 4;
        int c8  = (idx & 15) * 8;      // short offset in row
        if (q0 + r < HW && m0 + c8 + 8 <= M_) {
            uintx4 v = *(const uintx4*)&smem[r * K1_TS + c8];
            *(uintx4*)&En[(size_t)(q0 + r) * M_ + m0 + c8] = v;
        }
    }
    if (tid < 128) {
        const int gm = m0 + tid;
        if (gm < M_) atomicAdd(&dsum[(size_t)n * M_ + gm], colsum[tid]);
    }
#undef K1_STAGE
#undef K1_COMPUTE
}

// ---------------------------------------------------------------- mvs = bf16(mv / dsum[m])
__global__ __launch_bounds__(256) void k_mvs(
    const float* __restrict__ mval,   // [N][CV][M]
    const float* __restrict__ dsum,   // [N][M]
    uint16_t* __restrict__ mvs)       // [N][CV][M]
{
    unsigned i = blockIdx.x * 256 + threadIdx.x;
    unsigned base = i * 4u;
    unsigned n = base / (unsigned)(CV * M_);
    unsigned m = base % (unsigned)M_;
    floatx4 v = *(const floatx4*)&mval[base];
    floatx4 d = *(const floatx4*)&dsum[n * (unsigned)M_ + m];
    ushortx4 o;
    o[0] = f32_to_bf16(v[0] * (1.0f / d[0]));
    o[1] = f32_to_bf16(v[1] * (1.0f / d[1]));
    o[2] = f32_to_bf16(v[2] * (1.0f / d[2]));
    o[3] = f32_to_bf16(v[3] * (1.0f / d[3]));
    *(ushortx4*)&mvs[base] = o;
}

// ---------------------------------------------------------------- K2: 256c x 128q block, 64x128 wave tiles
// r10 PMC proved k2 is LDS-BW-bound (144KB/step-slot @ ~94B/cyc = measured
// 1533 cyc). Fix = geometry: wave tile 64x64 -> 64x128 cuts LDS reads/MFMA
// 0.5 -> 0.375 KB while doubling MFMA/step. Block = 256c x 128q, 4 waves
// stacked in c. Ring-3 depth-2, 24KB/buf (A 16KB + B 8KB) = 72KB -> 2
// blocks/CU. Grid 8q x 2c x 24nz = 384 blocks (1.5/CU avg; wall set by
// 2-block CUs). Ledger (6 loads/wave/stage): prologue 2 stages = 12 out;
// WAITV(6) drains tile t; stage t+2 -> buf (t+2)%3 (WAR-safe, same
// invariant as r10). Tail: WAITV(6)/WAITV(0).
#define K2_SPLITS 3
#define K2_BK 32
#define K2_STEPS 75   // 2400 / 32

__global__ __launch_bounds__(256, 2) void k2_big(
    const uint16_t* __restrict__ mvs,  // [N][CV][M] bf16 (already / dsum)
    const uint16_t* __restrict__ E,    // [N][HW][M] bf16
    float* __restrict__ partials)      // [3][N][CV][HW]
{
    __shared__ __align__(16) short lds2[36864];   // 3 bufs x (A 8192 + B 4096 shorts)

    // XCD swizzle: 384 blocks, 48/XCD (bijective, 384%8==0); q0 fastest so
    // the 8 q-blocks sharing an A-panel are adjacent on one XCD.
    const int bid = blockIdx.x + 8 * (blockIdx.y + 2 * blockIdx.z);
    const int swz = (bid & 7) * 48 + (bid >> 3);
    const int q0 = (swz & 7) << 7;           // 0..896
    const int c0 = ((swz >> 3) & 1) << 8;    // 0 or 256
    const int nz = swz >> 4;                 // 0..23
    const int n     = nz / K2_SPLITS;
    const int split = nz - n * K2_SPLITS;
    const int tid = threadIdx.x;

    const int lane = tid & 63;
    const int wid  = tid >> 6;       // wave owns c-range [wid*64, wid*64+64)
    const int fr   = lane & 15;
    const int quad = lane >> 4;

    // staging geometry: A = 16 chunks (16 rows c x 32 m, 1KB), wave owns 4;
    // B = 8 chunks, wave owns 2. Per-lane src offset: row rr, col cc.
    const int rr = lane >> 2;
    const int cc = (lane & 3) * 8;

    const uint16_t* Asrc = mvs + (size_t)(n * CV + c0) * M_ + split * 2400;
    const uint16_t* Bsrc = E + (size_t)n * HW * M_ + split * 2400;
    const uint16_t* Ap0 = Asrc + (size_t)(wid * 64 + rr) * M_ + cc;          // chunk j: +j*16*M_
    const uint16_t* Bp0 = Bsrc + (size_t)(q0 + wid * 32 + rr) * M_ + cc;     // chunk j: +j*16*M_

    floatx4 acc[4][8];
#pragma unroll
    for (int a = 0; a < 4; a++)
#pragma unroll
        for (int b = 0; b < 8; b++) acc[a][b] = (floatx4){0.f, 0.f, 0.f, 0.f};

#define K2_STAGE(buf, mo) do { \
    short* dA = lds2 + (buf) * 12288 + wid * 4 * 512; \
    short* dB = lds2 + (buf) * 12288 + 8192 + wid * 2 * 512; \
    gload_lds16(Ap0 + (mo), dA); \
    gload_lds16(Ap0 + (size_t)16 * M_ + (mo), dA + 512); \
    gload_lds16(Ap0 + (size_t)32 * M_ + (mo), dA + 1024); \
    gload_lds16(Ap0 + (size_t)48 * M_ + (mo), dA + 1536); \
    gload_lds16(Bp0 + (mo), dB); \
    gload_lds16(Bp0 + (size_t)16 * M_ + (mo), dB + 512); \
} while (0)

#define K2_COMPUTE(buf) do { \
    const short* bA = lds2 + (buf) * 12288; \
    const short* bB = bA + 8192; \
    const int k0 = quad * 8; \
    short8 af[4], bfr[8]; \
    _Pragma("unroll") \
    for (int t = 0; t < 4; t++) \
        af[t] = *(const short8*)&bA[(wid * 64 + t * 16 + fr) * 32 + k0]; \
    _Pragma("unroll") \
    for (int t = 0; t < 8; t++) \
        bfr[t] = *(const short8*)&bB[(t * 16 + fr) * 32 + k0]; \
    _Pragma("unroll") \
    for (int tc = 0; tc < 4; tc++) \
        _Pragma("unroll") \
        for (int tq = 0; tq < 8; tq++) \
            acc[tc][tq] = __builtin_amdgcn_mfma_f32_16x16x32_bf16( \
                af[tc], bfr[tq], acc[tc][tq], 0, 0, 0); \
} while (0)

    // ring-3 depth-2 over 75 tiles (tile->buf = tile%3)
    K2_STAGE(0, 0);
    K2_STAGE(1, K2_BK);
    for (int s = 0; s < 24; s++) {                // t = 3s..3s+2 (0..71)
        int mo = (3 * s + 2) * K2_BK;
        WAITV(6); BARRIER();
        K2_STAGE(2, mo); K2_COMPUTE(0);           // t=3s:   stage tile t+2 -> buf2
        WAITV(6); BARRIER();
        K2_STAGE(0, mo + K2_BK); K2_COMPUTE(1);   // t=3s+1: -> buf0
        WAITV(6); BARRIER();
        K2_STAGE(1, mo + 2 * K2_BK); K2_COMPUTE(2); // t=3s+2: -> buf1
    }
    // t=72: stage tile 74 -> buf2; compute tile 72 (buf0)
    WAITV(6); BARRIER();
    K2_STAGE(2, 74 * K2_BK); K2_COMPUTE(0);
    // t=73: compute tile 73 (buf1)
    WAITV(6); BARRIER();
    K2_COMPUTE(1);
    // t=74: compute tile 74 (buf2)
    WAITV(0); BARRIER();
    K2_COMPUTE(2);

    // epilogue: store partials. gc = c0 + wid*64 + tc*16 + quad*4 + i;
    // gq = q0 + tq*16 + fr (same verified MFMA C/D mapping as r4/r10).
    float* P = partials + ((size_t)split * N_ + n) * CV * HW;
#pragma unroll
    for (int tc = 0; tc < 4; tc++) {
#pragma unroll
        for (int tq = 0; tq < 8; tq++) {
            const int gq = q0 + tq * 16 + fr;
            if (gq < HW) {
#pragma unroll
                for (int i = 0; i < 4; i++) {
                    const int gc = c0 + wid * 64 + tc * 16 + quad * 4 + i;
                    P[(size_t)gc * HW + gq] = acc[tc][tq][i];
                }
            }
        }
    }
#undef K2_STAGE
#undef K2_COMPUTE
}

// ---------------------------------------------------------------- reduce 3 partials -> out mapped half
__global__ __launch_bounds__(256) void k_reduce3(const float* __restrict__ partials,
                                                 float* __restrict__ out) {
    unsigned i = blockIdx.x * 256 + threadIdx.x;
    unsigned e = i * 4u;
    unsigned n = e / (CV * HW);
    unsigned off = e - n * (CV * HW);
    const size_t stride = (size_t)N_ * CV * HW;
    const float* p = partials + (size_t)n * CV * HW + off;
    floatx4 a = *(const floatx4*)&p[0];
    floatx4 b = *(const floatx4*)&p[stride];
    floatx4 c = *(const floatx4*)&p[2 * stride];
    floatx4 s = a + b + c;
    *(floatx4*)&out[(size_t)n * (2 * CV * HW) + CV * HW + off] = s;
}

// ----------------------------------------------------------------
extern "C" void kernel_launch(void* const* d_in, const int* in_sizes, int n_in,
                              void* d_out, int out_size, void* d_ws, size_t ws_size,
                              hipStream_t stream) {
    const float* qkey = (const float*)d_in[0];  // [8][128][900]
    const float* qval = (const float*)d_in[1];  // [8][512][900]
    const float* mkey = (const float*)d_in[2];  // [8][128][7200]
    const float* mval = (const float*)d_in[3];  // [8][512][7200]
    float* out = (float*)d_out;                 // [8][1024][900]

    char* ws = (char*)d_ws;
    // E 103,680,000 | dsum 230,400 | (gap) | mvs 58,982,400 | partials 44,236,800
    // qkT/mkT alias partials (dead before k2_big writes partials).
    uint16_t* E        = (uint16_t*)ws;
    float*    dsum     = (float*)(ws + 103680000);
    uint16_t* mvs      = (uint16_t*)(ws + 104140800);
    float*    partials = (float*)(ws + 163123200);
    uint16_t* qkT      = (uint16_t*)(ws + 163123200);
    uint16_t* mkT      = (uint16_t*)(ws + 163123200 + 1843200);

    (void)in_sizes; (void)n_in; (void)out_size; (void)ws_size;

    k_prep<<<dim3(11953), 256, 0, stream>>>(qkey, mkey, qval, out, qkT, mkT, dsum);
    k1_gemm_exp<<<dim3(57, 8, N_), 256, 0, stream>>>(qkT, mkT, E, dsum);
    k_mvs<<<dim3((N_ * CV * M_) / 4 / 256), 256, 0, stream>>>(mval, dsum, mvs);
    k2_big<<<dim3(8, 2, N_ * K2_SPLITS), 256, 0, stream>>>(mvs, E, partials);
    k_reduce3<<<dim3((N_ * CV * HW) / 4 / 256), 256, 0, stream>>>(partials, out);
}